// Round 10
// baseline (1073.676 us; speedup 1.0000x reference)
//
#include <hip/hip_runtime.h>
#include <hip/hip_fp16.h>
#include <math.h>

#define TID threadIdx.x

typedef _Float16 h2vec __attribute__((ext_vector_type(2)));
typedef _Float16 f16x8 __attribute__((ext_vector_type(8)));
typedef float f32x4 __attribute__((ext_vector_type(4)));
typedef float f32x2v __attribute__((ext_vector_type(2)));

#if __has_builtin(__builtin_elementwise_fma)
#define EFMA(a, b, c) __builtin_elementwise_fma((a), (b), (c))
#else
static __device__ __forceinline__ f32x2v EFMA(f32x2v a, f32x2v b, f32x2v c) {
    f32x2v r;
    r.x = fmaf(a.x, b.x, c.x);
    r.y = fmaf(a.y, b.y, c.y);
    return r;
}
#endif

// fp16 pair dot into fp32 accumulator: v_dot2_f32_f16
static __device__ __forceinline__ float fdot2(unsigned a, unsigned b, float c) {
    h2vec av, bv;
    __builtin_memcpy(&av, &a, 4);
    __builtin_memcpy(&bv, &b, 4);
    return __builtin_amdgcn_fdot2(av, bv, c, false);
}

static __device__ __forceinline__ unsigned packh2(float a, float b) {
    __half2 hh = __floats2half2_rn(a, b);
    unsigned u;
    __builtin_memcpy(&u, &hh, 4);
    return u;
}

// Monotone float<->uint encoding for integer atomicMax on floats.
static __device__ __forceinline__ unsigned encf(float f) {
    unsigned u = __float_as_uint(f);
    return (u >> 31) ? ~u : (u | 0x80000000u);
}
static __device__ __forceinline__ float decf(unsigned e) {
    unsigned u = (e >> 31) ? (e & 0x7fffffffu) : ~e;
    return __uint_as_float(u);
}

// Wave-uniform sum via DPP ladder; only lane63 true total, readlane broadcasts.
static __device__ __forceinline__ int wave_sum(int v) {
    v += __builtin_amdgcn_update_dpp(0, v, 0x111, 0xf, 0xf, true);  // row_shr:1
    v += __builtin_amdgcn_update_dpp(0, v, 0x112, 0xf, 0xf, true);  // row_shr:2
    v += __builtin_amdgcn_update_dpp(0, v, 0x114, 0xf, 0xf, true);  // row_shr:4
    v += __builtin_amdgcn_update_dpp(0, v, 0x118, 0xf, 0xf, true);  // row_shr:8
    v += __builtin_amdgcn_update_dpp(0, v, 0x142, 0xf, 0xf, true);  // row_bcast15
    v += __builtin_amdgcn_update_dpp(0, v, 0x143, 0xf, 0xf, true);  // row_bcast31
    return __builtin_amdgcn_readlane(v, 63);
}

// u64 max with partner brought in by DPP; bound_ctrl=true shifts in 0 (identity).
template <int CTRL>
static __device__ __forceinline__ unsigned long long dpp_max_u64(unsigned long long k) {
    int lo = (int)(unsigned)(k & 0xffffffffULL);
    int hi = (int)(unsigned)(k >> 32);
    int lo2 = __builtin_amdgcn_update_dpp(0, lo, CTRL, 0xf, 0xf, true);
    int hi2 = __builtin_amdgcn_update_dpp(0, hi, CTRL, 0xf, 0xf, true);
    unsigned long long k2 = ((unsigned long long)(unsigned)hi2 << 32) | (unsigned)lo2;
    return k2 > k ? k2 : k;
}

// ---------------------------------------------------------------------------
// fp32 -> fp16 B-fragment pack for mfma_f32_16x16x32_f16 (one slot per t).
// ---------------------------------------------------------------------------
static __device__ __forceinline__ void pack_slot(const float* __restrict__ W,
                                                 unsigned* __restrict__ out,
                                                 int K, int ncols, int t) {
    int lane = t & 63;
    int frag = t >> 6;
    int nct = ncols >> 4;
    int ks = frag / nct, ct = frag - ks * nct;
    int kbase = (ks << 5) + ((lane >> 4) << 3);
    int cc = (ct << 4) + (lane & 15);
    unsigned o[4];
#pragma unroll
    for (int i = 0; i < 4; ++i) {
        int k0 = kbase + 2 * i, k1 = kbase + 2 * i + 1;
        float f0 = (k0 < K) ? W[(size_t)k0 * ncols + cc] : 0.f;
        float f1 = (k1 < K) ? W[(size_t)k1 * ncols + cc] : 0.f;
        o[i] = packh2(f0, f1);
    }
    *(uint4*)&out[(size_t)t * 4] = make_uint4(o[0], o[1], o[2], o[3]);
}

// ---------------------------------------------------------------------------
// Curvature: per-point 10-NN covariance, lambda_min / sum(lambda).
// Round-5 proven: 4 sub-lanes per point, disjoint 512-ranges, exact
// lexicographic (d2, idx) 4-way merge — bit-identical, measured -122 us.
// ---------------------------------------------------------------------------
__global__ __launch_bounds__(256) void curv_kernel(const float* __restrict__ pos,
                                                   float* __restrict__ curv) {
    __shared__ float4 sp[2048];
    __shared__ float smd[64][40];   // [pt][sub*10+t]
    __shared__ int smi[64][40];
    int cloud = blockIdx.x >> 5;
    int base = cloud << 11;
    for (int j = TID; j < 2048; j += 256) {
        const float* p = pos + (size_t)(base + j) * 3;
        float x = p[0], y = p[1], z = p[2];
        sp[j] = make_float4(x, y, z, fmaf(x, x, fmaf(y, y, z * z)));
    }
    __syncthreads();
    int pt = TID >> 2;                       // 0..63: point within block
    int sub = TID & 3;                       // 0..3: candidate range
    int li = ((blockIdx.x & 31) << 6) + pt;  // point within cloud
    float4 pi = sp[li];
    float bd[10];
    int bi[10];
#pragma unroll
    for (int t = 0; t < 10; ++t) { bd[t] = 3.0e38f; bi[t] = 0; }
    int j0 = sub << 9;
    for (int jj = 0; jj < 512; ++jj) {
        int j = j0 + jj;
        float4 pj = sp[j];
        float dot = fmaf(pi.x, pj.x, fmaf(pi.y, pj.y, pi.z * pj.z));
        float d2 = pi.w + pj.w - 2.0f * dot;   // same form as reference _sqdist
        if (d2 < bd[9]) {
            bd[9] = d2; bi[9] = j;
#pragma unroll
            for (int t = 9; t > 0; --t) {
                if (bd[t] < bd[t - 1]) {
                    float td = bd[t]; bd[t] = bd[t - 1]; bd[t - 1] = td;
                    int ti = bi[t]; bi[t] = bi[t - 1]; bi[t - 1] = ti;
                }
            }
        }
    }
#pragma unroll
    for (int t = 0; t < 10; ++t) {
        smd[pt][sub * 10 + t] = bd[t];
        smi[pt][sub * 10 + t] = bi[t];
    }
    __syncthreads();
    // exact 4-way lex-(d2,idx) merge; all 4 subs compute redundantly
    float d0 = smd[pt][0], d1 = smd[pt][10], d2h = smd[pt][20], d3 = smd[pt][30];
    int i0 = smi[pt][0], i1 = smi[pt][10], i2 = smi[pt][20], i3 = smi[pt][30];
    int h0 = 0, h1 = 0, h2c = 0, h3 = 0;
    int mbi[10];
#pragma unroll
    for (int t = 0; t < 10; ++t) {
        bool a01 = (d1 < d0) || (d1 == d0 && i1 < i0);
        float dA = a01 ? d1 : d0; int iA = a01 ? i1 : i0;
        bool a23 = (d3 < d2h) || (d3 == d2h && i3 < i2);
        float dB = a23 ? d3 : d2h; int iB = a23 ? i3 : i2;
        bool ab = (dB < dA) || (dB == dA && iB < iA);
        mbi[t] = ab ? iB : iA;
        if (ab) {
            if (a23) { ++h3; d3 = (h3 < 10) ? smd[pt][30 + h3] : 3.0e38f;
                       i3 = (h3 < 10) ? smi[pt][30 + h3] : 0x7fffffff; }
            else     { ++h2c; d2h = (h2c < 10) ? smd[pt][20 + h2c] : 3.0e38f;
                       i2 = (h2c < 10) ? smi[pt][20 + h2c] : 0x7fffffff; }
        } else {
            if (a01) { ++h1; d1 = (h1 < 10) ? smd[pt][10 + h1] : 3.0e38f;
                       i1 = (h1 < 10) ? smi[pt][10 + h1] : 0x7fffffff; }
            else     { ++h0; d0 = (h0 < 10) ? smd[pt][h0] : 3.0e38f;
                       i0 = (h0 < 10) ? smi[pt][h0] : 0x7fffffff; }
        }
    }
    if (sub != 0) return;
    double sx = 0, sy = 0, sz = 0;
#pragma unroll
    for (int t = 0; t < 10; ++t) { float4 p = sp[mbi[t]]; sx += p.x; sy += p.y; sz += p.z; }
    double mx = sx / 10.0, my = sy / 10.0, mz = sz / 10.0;
    double cxx = 0, cxy = 0, cxz = 0, cyy = 0, cyz = 0, czz = 0;
#pragma unroll
    for (int t = 0; t < 10; ++t) {
        float4 p = sp[mbi[t]];
        double dx = p.x - mx, dy = p.y - my, dz = p.z - mz;
        cxx += dx * dx; cxy += dx * dy; cxz += dx * dz;
        cyy += dy * dy; cyz += dy * dz; czz += dz * dz;
    }
    cxx /= 10.0; cxy /= 10.0; cxz /= 10.0; cyy /= 10.0; cyz /= 10.0; czz /= 10.0;
    double q = (cxx + cyy + czz) / 3.0;
    double b00 = cxx - q, b11 = cyy - q, b22 = czz - q;
    double p2 = b00 * b00 + b11 * b11 + b22 * b22 +
                2.0 * (cxy * cxy + cxz * cxz + cyz * cyz);
    double lmin;
    if (p2 <= 0.0) {
        lmin = q;
    } else {
        double p = sqrt(p2 / 6.0);
        double inv = 1.0 / p;
        double c00 = b00 * inv, c01 = cxy * inv, c02 = cxz * inv;
        double c11 = b11 * inv, c12 = cyz * inv, c22 = b22 * inv;
        double detB = c00 * (c11 * c22 - c12 * c12)
                    - c01 * (c01 * c22 - c12 * c02)
                    + c02 * (c01 * c12 - c11 * c02);
        double r = 0.5 * detB;
        r = fmin(1.0, fmax(-1.0, r));
        double phi = acos(r) / 3.0;
        lmin = q + 2.0 * p * cos(phi + 2.0943951023931953);  // smallest eigenvalue
    }
    double s3 = cxx + cyy + czz;
    curv[base + li] = (float)(lmin / (s3 + 1e-8));
}

// ---------------------------------------------------------------------------
// Weighted FPS body — round-0 proven structure (measured best): 4 waves,
// packed f32x2 update, u64 key tree per lane, u64 DPP max ladder, lane63
// posts 1 record/wave, single barrier, fold 4. Key=(score_bits<<32)|(2047-idx).
// Three structural variants + setprio(3)-on-fps1 all measured SLOWER — do not
// touch the exchange or fps1's priority.
// ---------------------------------------------------------------------------
template <int N, int M, int SLOTS>
static __device__ void fps_body(
    const float* __restrict__ srcpos, int stride, const float* __restrict__ srccurv,
    int cloud, float4* __restrict__ outPos, float* __restrict__ outCurv,
    float* __restrict__ outA, int ldA,
    float4* sp, int* sidx, unsigned long long* rec /* [8] */) {
    constexpr int PAIRS = SLOTS / 2;
    const float* cp = srcpos + (size_t)cloud * N * stride;
    for (int j = TID; j < N; j += 256)
        sp[j] = make_float4(cp[j * stride], cp[j * stride + 1], cp[j * stride + 2], 0.f);
    if (TID == 0) sidx[0] = 0;
    __syncthreads();
    f32x2v px[PAIRS], py[PAIRS], pz[PAIRS], md[PAIRS], wvv[PAIRS];
#pragma unroll
    for (int s = 0; s < PAIRS; ++s) {
        int p0 = ((2 * s) << 8) + TID, p1 = ((2 * s + 1) << 8) + TID;
        float4 q0 = sp[p0], q1 = sp[p1];
        px[s].x = q0.x; px[s].y = q1.x;
        py[s].x = q0.y; py[s].y = q1.y;
        pz[s].x = q0.z; pz[s].y = q1.z;
        md[s].x = 3.0e38f; md[s].y = 3.0e38f;
        wvv[s].x = fmaf(10.0f, srccurv[cloud * N + p0], 1.0f);
        wvv[s].y = fmaf(10.0f, srccurv[cloud * N + p1], 1.0f);
    }
    int lane = TID & 63, w4 = TID >> 6;
    float4 c0 = sp[0];
    float cx = c0.x, cy = c0.y, cz = c0.z;
    for (int t = 1; t < M; ++t) {
        f32x2v cxv, cyv, czv;
        cxv.x = cx; cxv.y = cx; cyv.x = cy; cyv.y = cy; czv.x = cz; czv.y = cz;
        unsigned long long kk[PAIRS];
#pragma unroll
        for (int s = 0; s < PAIRS; ++s) {
            f32x2v dx = px[s] - cxv, dy = py[s] - cyv, dz = pz[s] - czv;
            f32x2v nd = EFMA(dx, dx, EFMA(dy, dy, dz * dz));
            f32x2v m2 = __builtin_elementwise_min(md[s], nd);
            md[s] = m2;
            f32x2v sc = m2 * wvv[s];
            // score >= 0 -> float bits monotone under unsigned compare
            unsigned long long k0 =
                ((unsigned long long)__float_as_uint(sc.x) << 32) |
                (unsigned)(2047 - (((2 * s) << 8) + TID));
            unsigned long long k1 =
                ((unsigned long long)__float_as_uint(sc.y) << 32) |
                (unsigned)(2047 - (((2 * s + 1) << 8) + TID));
            kk[s] = k0 > k1 ? k0 : k1;
        }
        unsigned long long k = kk[0];
#pragma unroll
        for (int s = 1; s < PAIRS; ++s) k = kk[s] > k ? kk[s] : k;
        k = dpp_max_u64<0x111>(k);   // row_shr:1
        k = dpp_max_u64<0x112>(k);   // row_shr:2
        k = dpp_max_u64<0x114>(k);   // row_shr:4
        k = dpp_max_u64<0x118>(k);   // row_shr:8
        k = dpp_max_u64<0x142>(k);   // row_bcast15
        k = dpp_max_u64<0x143>(k);   // row_bcast31 -> lane63 has wave max
        int pbase = (t & 1) << 2;
        if (lane == 63) rec[pbase | w4] = k;
        __syncthreads();
        unsigned long long k0 = rec[pbase + 0];
        unsigned long long k1 = rec[pbase + 1];
        unsigned long long k2 = rec[pbase + 2];
        unsigned long long k3 = rec[pbase + 3];
        unsigned long long ka = k0 > k1 ? k0 : k1;
        unsigned long long kb = k2 > k3 ? k2 : k3;
        unsigned long long km = ka > kb ? ka : kb;
        int nbix = 2047 - (int)(unsigned)(km & 0xffffffffULL);  // uniform winner
        if (TID == 0) sidx[t] = nbix;
        float4 cc = sp[nbix];        // uniform (broadcast) read
        cx = cc.x; cy = cc.y; cz = cc.z;
    }
    __syncthreads();
    for (int j = TID; j < M; j += 256) {
        int id = sidx[j];
        float4 qv = sp[id];
        outPos[cloud * M + j] = qv;
        if (outCurv) outCurv[cloud * M + j] = srccurv[cloud * N + id];
        if (outA) {
            float* a = outA + (size_t)(cloud * M + j) * ldA;
            a[256] = qv.x; a[257] = qv.y; a[258] = qv.z;
        }
    }
}

// ---------------------------------------------------------------------------
// fps1 + weight packing in one launch. Blocks 0-7: fps1 (serial, 8 CUs for
// ~425 us). Blocks 8-403: fragment-pack the 8 weight matrices (independent
// of fps1; hidden entirely under its shadow). Block 8 inits gfeat encodings.
// ---------------------------------------------------------------------------
__global__ __launch_bounds__(256, 1) void fps1_pack_kernel(
    const float* __restrict__ pos, const float* __restrict__ curv,
    float4* __restrict__ pos1, float* __restrict__ curv1,
    const float* __restrict__ Wc, const float* __restrict__ Wa,
    const float* __restrict__ Wb, const float* __restrict__ W3a,
    const float* __restrict__ W3b, const float* __restrict__ W3c,
    const float* __restrict__ W1b, const float* __restrict__ W1c,
    unsigned* __restrict__ WcH, unsigned* __restrict__ WaH,
    unsigned* __restrict__ WbH, unsigned* __restrict__ W3aH,
    unsigned* __restrict__ W3bH, unsigned* __restrict__ W3cH,
    unsigned* __restrict__ W1bH, unsigned* __restrict__ W1cH,
    unsigned* __restrict__ gfeatE) {
    __shared__ float4 sp[2048];
    __shared__ int sidx[1024];
    __shared__ unsigned long long rec[8];
    if (blockIdx.x < 8) {
        fps_body<2048, 1024, 8>(pos, 3, curv, blockIdx.x, pos1, curv1, nullptr, 0,
                                sp, sidx, rec);
        return;
    }
    int b = blockIdx.x - 8;
    if (b == 0)
        for (int i = TID; i < 8192; i += 256) gfeatE[i] = 0u;  // enc identity
    if (b < 16)        pack_slot(Wc,  WcH,  128, 256,  b * 256 + TID);
    else if (b < 26)   pack_slot(Wa,  WaH,  131, 128,  (b - 16) * 256 + TID);
    else if (b < 34)   pack_slot(Wb,  WbH,  128, 128,  (b - 26) * 256 + TID);
    else if (b < 70)   pack_slot(W3a, W3aH, 259, 256,  (b - 34) * 256 + TID);
    else if (b < 134)  pack_slot(W3b, W3bH, 256, 512,  (b - 70) * 256 + TID);
    else if (b < 390)  pack_slot(W3c, W3cH, 512, 1024, (b - 134) * 256 + TID);
    else if (b < 392)  pack_slot(W1b, W1bH, 64, 64,    (b - 390) * 256 + TID);
    else               pack_slot(W1c, W1cH, 64, 128,   (b - 392) * 256 + TID);
}

// ---------------------------------------------------------------------------
// Exact top-64 (smallest d2, idx tie-break), register-resident, atomic-free.
// NCH chunks of 64 candidates (c <= NCH*64). Fast path (excess <= 24): remove
// the excess LARGEST lex keys by repeated DPP wave-max. Fallback: bit-search
// on register keys. Keep-set identical to the original LDS select_k64; sel
// ORDER differs, which is fine — aggregation is max (order-free) and the
// row-validity mask is count-based.
// ---------------------------------------------------------------------------
template <int NCH>
static __device__ __forceinline__ int select_k64_reg(
    const unsigned* __restrict__ ck, const int* __restrict__ ci,
    int c, int lane, int* sel, int* nbOut) {
    if (c <= 64) {
        *nbOut = c;
        return (lane < c) ? ci[lane] : 0;
    }
    unsigned long long kq[NCH];
    bool act[NCH];
#pragma unroll
    for (int q = 0; q < NCH; ++q) {
        int idx = (q << 6) + lane;
        bool v = idx < c;
        act[q] = v;
        kq[q] = v ? (((unsigned long long)ck[idx] << 32) | (unsigned)ci[idx]) : 0ULL;
    }
    int excess = c - 64;
    if (excess <= 24) {
        for (int r = 0; r < excess; ++r) {
            unsigned long long k = 0;
#pragma unroll
            for (int q = 0; q < NCH; ++q) {
                unsigned long long kc = act[q] ? kq[q] : 0ULL;
                k = kc > k ? kc : k;
            }
            k = dpp_max_u64<0x111>(k);
            k = dpp_max_u64<0x112>(k);
            k = dpp_max_u64<0x114>(k);
            k = dpp_max_u64<0x118>(k);
            k = dpp_max_u64<0x142>(k);
            k = dpp_max_u64<0x143>(k);
            unsigned klo = (unsigned)__builtin_amdgcn_readlane(
                (int)(unsigned)(k & 0xffffffffULL), 63);
            unsigned khi = (unsigned)__builtin_amdgcn_readlane(
                (int)(unsigned)(k >> 32), 63);
            unsigned long long km = ((unsigned long long)khi << 32) | klo;
#pragma unroll
            for (int q = 0; q < NCH; ++q)
                if (act[q] && kq[q] == km) act[q] = false;
        }
    } else {
        unsigned T = 0;
        for (int bit = 31; bit >= 0; --bit) {
            unsigned mid = T | (1u << bit);
            int cl = 0;
#pragma unroll
            for (int q = 0; q < NCH; ++q)
                cl += (act[q] && (unsigned)(kq[q] >> 32) < mid) ? 1 : 0;
            if (wave_sum(cl) < 64) T = mid;
        }
        int cl = 0;
#pragma unroll
        for (int q = 0; q < NCH; ++q)
            cl += (act[q] && (unsigned)(kq[q] >> 32) < T) ? 1 : 0;
        int need = 64 - wave_sum(cl);
        int TI = 0;
        for (int bit = 11; bit >= 0; --bit) {
            int mid = TI | (1 << bit);
            int ce = 0;
#pragma unroll
            for (int q = 0; q < NCH; ++q)
                ce += (act[q] && (unsigned)(kq[q] >> 32) == T &&
                       (int)(unsigned)(kq[q] & 0xffffffffULL) < mid) ? 1 : 0;
            if (wave_sum(ce) < need) TI = mid;
        }
#pragma unroll
        for (int q = 0; q < NCH; ++q) {
            unsigned hi = (unsigned)(kq[q] >> 32);
            int lo = (int)(unsigned)(kq[q] & 0xffffffffULL);
            act[q] = act[q] && (hi < T || (hi == T && lo <= TI));
        }
    }
    int base = 0;
#pragma unroll
    for (int q = 0; q < NCH; ++q) {
        unsigned long long m = __ballot(act[q]);
        if (act[q]) {
            int off = __popcll(m & ((1ULL << lane) - 1));
            sel[base + off] = (int)(unsigned)(kq[q] & 0xffffffffULL);
        }
        base += __popcll(m);
    }
    *nbOut = 64;
    return sel[lane];
}

// ---------------------------------------------------------------------------
// SA1 conv body (3->64->64->128). Round-9 proven: L2/L3 as MFMA GEMMs, h1
// fp32 scalar, fp16 LDS rows (36-dword stride), in-place L2 write-back,
// masked row-max L3. Value path verified absmax 0.0.
// ---------------------------------------------------------------------------
union U1 {
    struct {
        float4 sp[2048];
        unsigned ck[4][256];
        int ci[4][256];
        int sel[4][64];
    } p;                      // 41 KB
    unsigned hs[4][2304];     // 36 KB: 64 rows x 36 dwords (h1 then h2, fp16 pairs)
};

static __device__ void conv1_body(
    int bid, U1& u,
    const float* __restrict__ pos, const float4* __restrict__ pos1,
    const float* __restrict__ W1, const float* __restrict__ B1,
    const unsigned* __restrict__ W1bH, const float* __restrict__ B2,
    const unsigned* __restrict__ W1cH, const float* __restrict__ B3,
    float* __restrict__ x1) {
    __shared__ int nbs[4];
    int cloud = bid >> 8;
    int w4 = TID >> 6, lane = TID & 63;
    int quad = lane >> 4, l15 = lane & 15;
    int centb = (bid & 255) << 2;
    int g = (cloud << 10) + centb + w4;
    int base = cloud << 11;
    for (int j = TID; j < 2048; j += 256) {
        const float* p = pos + (size_t)(base + j) * 3;
        u.p.sp[j] = make_float4(p[0], p[1], p[2], 0.f);
    }
    __syncthreads();
    float4 cq = pos1[g];
    double cx = cq.x, cy = cq.y, cz = cq.z;
    int cnt = 0;   // wave-uniform running candidate count
    for (int s = 0; s < 32; ++s) {
        int j = (s << 6) + lane;
        float4 pj = u.p.sp[j];
        double dx = (double)pj.x - cx, dy = (double)pj.y - cy, dz = (double)pj.z - cz;
        double d2 = dx * dx + dy * dy + dz * dz;
        bool in = (d2 <= 0.2 * 0.2);
        unsigned long long m = __ballot(in);
        if (in) {
            int p = cnt + __popcll(m & ((1ULL << lane) - 1));
            if (p < 256) {
                u.p.ck[w4][p] = __float_as_uint((float)d2);
                u.p.ci[w4][p] = j;
            }
        }
        cnt += __popcll(m);
    }
    int c = min(cnt, 256);
    int nb;
    int idxn = select_k64_reg<4>(u.p.ck[w4], u.p.ci[w4], c, lane, u.p.sel[w4], &nb);
    if (lane == 0) nbs[w4] = nb;
    float4 pn = u.p.sp[idxn];
    float rx = pn.x - cq.x, ry = pn.y - cq.y, rz = pn.z - cq.z;
    // h1 fp32 (exact): 64 ch, 3 FMAs each
    float h1[64];
#pragma unroll
    for (int cc2 = 0; cc2 < 64; ++cc2) {
        float v = fmaf(rx, W1[cc2], fmaf(ry, W1[64 + cc2], fmaf(rz, W1[128 + cc2], B1[cc2])));
        h1[cc2] = fmaxf(v, 0.f);
    }
    __syncthreads();   // all waves done with p region -> hs free
    // stage h1 -> hs fp16 pairs, row = lane, 36-dword stride
    {
        unsigned* row = &u.hs[w4][lane * 36];
#pragma unroll
        for (int q = 0; q < 8; ++q) {
            *(uint4*)&row[q << 2] =
                make_uint4(packh2(h1[8 * q + 0], h1[8 * q + 1]),
                           packh2(h1[8 * q + 2], h1[8 * q + 3]),
                           packh2(h1[8 * q + 4], h1[8 * q + 5]),
                           packh2(h1[8 * q + 6], h1[8 * q + 7]));
        }
    }
    __syncthreads();   // h1 rows visible (same wave + lockstep safety)
    // --- L2 MFMA: h2[64x64] = h1 @ W1b (K=64: 2 ks; 64 cols: 4 ct) ---
    // Preload ALL A-frags first (removes in-place RAW hazard), then per rt
    // compute 4 ct tiles and write h2 back into the same rows.
    {
        f16x8 bfrag[2][4];
#pragma unroll
        for (int ks = 0; ks < 2; ++ks)
#pragma unroll
            for (int ct = 0; ct < 4; ++ct) {
                uint4 bv = *(const uint4*)&W1bH[(size_t)(
                    (((ks << 2) | ct) << 6) | lane) << 2];
                __builtin_memcpy(&bfrag[ks][ct], &bv, 16);
            }
        f16x8 af[4][2];
#pragma unroll
        for (int rt = 0; rt < 4; ++rt)
#pragma unroll
            for (int ks = 0; ks < 2; ++ks) {
                uint4 av = *(const uint4*)&u.hs[w4][((rt << 4) + l15) * 36 +
                                                    (((ks << 2) | quad) << 2)];
                __builtin_memcpy(&af[rt][ks], &av, 16);
            }
        float ba4[4];
#pragma unroll
        for (int ct = 0; ct < 4; ++ct) ba4[ct] = B2[(ct << 4) + l15];
#pragma unroll
        for (int rt = 0; rt < 4; ++rt) {
#pragma unroll
            for (int ct = 0; ct < 4; ++ct) {
                f32x4 acc = {0.f, 0.f, 0.f, 0.f};
#pragma unroll
                for (int ks = 0; ks < 2; ++ks)
                    acc = __builtin_amdgcn_mfma_f32_16x16x32_f16(
                        af[rt][ks], bfrag[ks][ct], acc, 0, 0, 0);
#pragma unroll
                for (int r = 0; r < 4; ++r) {
                    float v = fmaxf(acc[r] + ba4[ct], 0.f);
                    float vp = __shfl_xor(v, 1, 64);
                    if (!(l15 & 1)) {
                        int rowi = (rt << 4) + (quad << 2) + r;
                        u.hs[w4][rowi * 36 + (ct << 3) + (l15 >> 1)] = packh2(v, vp);
                    }
                }
            }
        }
    }
    __syncthreads();   // h2 rows + nbs visible block-wide
    // --- L3 MFMA: msg[64x128] = h2 @ W1c (K=64: 2 ks; 128 cols: 8 ct).
    // Wave owns 2 col-tiles (w4*2, w4*2+1), loops 4 centroids; masked row-max.
    {
        int ct2 = w4 << 1;
        f16x8 cfrag[2][2];   // [ctl][ks]
#pragma unroll
        for (int ctl = 0; ctl < 2; ++ctl)
#pragma unroll
            for (int ks = 0; ks < 2; ++ks) {
                uint4 bv = *(const uint4*)&W1cH[(size_t)(
                    (((ks << 3) | (ct2 + ctl)) << 6) | lane) << 2];
                __builtin_memcpy(&cfrag[ctl][ks], &bv, 16);
            }
#pragma unroll 1
        for (int cent = 0; cent < 4; ++cent) {
            int nbc = nbs[cent];
            float runM[2][4];
#pragma unroll
            for (int ctl = 0; ctl < 2; ++ctl)
#pragma unroll
                for (int r = 0; r < 4; ++r) runM[ctl][r] = -1e30f;
#pragma unroll
            for (int rt = 0; rt < 4; ++rt) {
                f16x8 af[2];
#pragma unroll
                for (int ks = 0; ks < 2; ++ks) {
                    uint4 av = *(const uint4*)&u.hs[cent][((rt << 4) + l15) * 36 +
                                                          (((ks << 2) | quad) << 2)];
                    __builtin_memcpy(&af[ks], &av, 16);
                }
#pragma unroll
                for (int ctl = 0; ctl < 2; ++ctl) {
                    f32x4 acc = {0.f, 0.f, 0.f, 0.f};
#pragma unroll
                    for (int ks = 0; ks < 2; ++ks)
                        acc = __builtin_amdgcn_mfma_f32_16x16x32_f16(
                            af[ks], cfrag[ctl][ks], acc, 0, 0, 0);
                    int nb0 = (rt << 4) + (quad << 2);
#pragma unroll
                    for (int r = 0; r < 4; ++r) {
                        float v = (nb0 + r < nbc) ? acc[r] : -1e30f;
                        runM[ctl][r] = fmaxf(runM[ctl][r], v);
                    }
                }
            }
#pragma unroll
            for (int ctl = 0; ctl < 2; ++ctl) {
                float m = fmaxf(fmaxf(runM[ctl][0], runM[ctl][1]),
                                fmaxf(runM[ctl][2], runM[ctl][3]));
                m = fmaxf(m, __shfl_xor(m, 16, 64));
                m = fmaxf(m, __shfl_xor(m, 32, 64));
                if (lane < 16) {
                    int cc = ((ct2 + ctl) << 4) | l15;
                    x1[(size_t)((cloud << 10) + centb + cent) * 128 + cc] = m + B3[cc];
                }
            }
        }
    }
}

// ---------------------------------------------------------------------------
// Merged launch: blocks 0-7 run fps2 (1024->256) at wave priority 1 — with
// conv1 now MFMA-fast, the serial fps2 chain is the exposed tail; priority
// lets it win issue arbitration against co-resident conv1 waves and re-hide
// under conv1's shadow. (Round 6's null was when conv1 was slow / fps2 hidden;
// round 6's fps1-setprio regression was a dedicated-CU pin, not arbitration.)
// Blocks 8.. run conv1 at default priority. 3 blocks/CU.
// ---------------------------------------------------------------------------
union UM {
    U1 c;
    struct {
        float4 sp[1024];
        unsigned long long rec[8];
        int sidx[256];
    } f;
};

__global__ __launch_bounds__(256, 3) void fps2_conv1_kernel(
    const float* __restrict__ pos, const float4* __restrict__ pos1,
    const float* __restrict__ curv1, float4* __restrict__ pos2,
    float* __restrict__ Abuf,
    const float* __restrict__ W1, const float* __restrict__ B1,
    const unsigned* __restrict__ W1bH, const float* __restrict__ B2,
    const unsigned* __restrict__ W1cH, const float* __restrict__ B3,
    float* __restrict__ x1) {
    __shared__ UM u;
    if (blockIdx.x < 8) {
        __builtin_amdgcn_s_setprio(1);   // latency-critical serial chain
        fps_body<1024, 256, 4>((const float*)pos1, 4, curv1, blockIdx.x, pos2,
                               nullptr, Abuf, 260, u.f.sp, u.f.sidx, u.f.rec);
    } else {
        conv1_body(blockIdx.x - 8, u.c, pos, pos1, W1, B1, W1bH, B2, W1cH, B3, x1);
    }
}

// ---------------------------------------------------------------------------
// SA2: radius r=0.4 grouping + PointNetConv(131->128->128->256), all 3 layers
// as MFMA GEMMs. Round-8: ballot-compaction grouping + register select.
// ---------------------------------------------------------------------------
union U2 {
    struct {
        float4 sp[1024];
        unsigned ck[4][512];
        int ci[4][512];
        int sel[4][64];
    } p;
    unsigned xs[4][5376];   // 84 dwords/row x 64 rows; h2s[cent]=xs[cent][0..4095]
};

__global__ __launch_bounds__(256, 1) void conv2_kernel(
    const float4* __restrict__ pos1, const float4* __restrict__ pos2,
    const float* __restrict__ x1,
    const unsigned* __restrict__ WaH, const float* __restrict__ Ba,
    const unsigned* __restrict__ WbH, const float* __restrict__ Bb,
    const unsigned* __restrict__ WcH, const float* __restrict__ Bc,
    float* __restrict__ Aout) {
    __shared__ U2 u;
    __shared__ unsigned h1s[4][4352];   // 68 dwords/row x 64 rows (fp16 pairs)
    __shared__ int nbs[4];
    int cloud = blockIdx.x >> 6;
    int w4 = TID >> 6, lane = TID & 63;
    int centb = (blockIdx.x & 63) << 2;
    int g = (cloud << 8) + centb + w4;
    int quad = lane >> 4, l15 = lane & 15;
    for (int j = TID; j < 1024; j += 256) u.p.sp[j] = pos1[(cloud << 10) + j];
    __syncthreads();
    float4 cq = pos2[g];
    double cx = cq.x, cy = cq.y, cz = cq.z;
    int cnt = 0;   // wave-uniform running candidate count
    for (int s = 0; s < 16; ++s) {
        int j = (s << 6) + lane;
        float4 pj = u.p.sp[j];
        double dx = (double)pj.x - cx, dy = (double)pj.y - cy, dz = (double)pj.z - cz;
        double d2 = dx * dx + dy * dy + dz * dz;
        bool in = (d2 <= 0.4 * 0.4);
        unsigned long long m = __ballot(in);
        if (in) {
            int p = cnt + __popcll(m & ((1ULL << lane) - 1));
            if (p < 512) {
                u.p.ck[w4][p] = __float_as_uint((float)d2);
                u.p.ci[w4][p] = j;
            }
        }
        cnt += __popcll(m);
    }
    int c = min(cnt, 512);
    int nb;
    int idxn = select_k64_reg<8>(u.p.ck[w4], u.p.ci[w4], c, lane, u.p.sel[w4], &nb);
    if (lane == 0) nbs[w4] = nb;
    float4 pn = u.p.sp[idxn];
    float rx = pn.x - cq.x, ry = pn.y - cq.y, rz = pn.z - cq.z;
    __syncthreads();   // grouping LDS dead -> xs may overwrite
    // --- stage xs: lane = row, gathered x1 row as fp16 + rel + zero pad ---
    {
        const float4* xr = (const float4*)(x1 + (size_t)((cloud << 10) + idxn) * 128);
        unsigned* row = &u.xs[w4][lane * 84];
#pragma unroll
        for (int q = 0; q < 16; ++q) {
            float4 a = xr[q * 2], b = xr[q * 2 + 1];
            *(uint4*)&row[q << 2] = make_uint4(packh2(a.x, a.y), packh2(a.z, a.w),
                                               packh2(b.x, b.y), packh2(b.z, b.w));
        }
        *(uint4*)&row[64] = make_uint4(packh2(rx, ry), packh2(rz, 0.f), 0u, 0u);
        *(uint4*)&row[68] = make_uint4(0u, 0u, 0u, 0u);
        *(uint4*)&row[72] = make_uint4(0u, 0u, 0u, 0u);
        *(uint4*)&row[76] = make_uint4(0u, 0u, 0u, 0u);
    }
    // --- L1 MFMA: h1[64 x 128] = xs[64 x 160] @ WaH; bias+relu; pack to h1s ---
    float ba8[8];
#pragma unroll
    for (int ct = 0; ct < 8; ++ct) ba8[ct] = Ba[(ct << 4) + l15];
#pragma unroll 1
    for (int ct = 0; ct < 8; ++ct) {
        f16x8 bfrag[5];
#pragma unroll
        for (int ks = 0; ks < 5; ++ks) {
            uint4 bv = *(const uint4*)&WaH[(size_t)((((ks << 3) | ct) << 6) | lane) << 2];
            __builtin_memcpy(&bfrag[ks], &bv, 16);
        }
#pragma unroll
        for (int rt = 0; rt < 4; ++rt) {
            f32x4 acc = {0.f, 0.f, 0.f, 0.f};
#pragma unroll
            for (int ks = 0; ks < 5; ++ks) {
                f16x8 af;
                uint4 av = *(const uint4*)&u.xs[w4][((rt << 4) + l15) * 84 +
                                                    (((ks << 2) + quad) << 2)];
                __builtin_memcpy(&af, &av, 16);
                acc = __builtin_amdgcn_mfma_f32_16x16x32_f16(af, bfrag[ks], acc, 0, 0, 0);
            }
#pragma unroll
            for (int r = 0; r < 4; ++r) {
                float v = fmaxf(acc[r] + ba8[ct], 0.f);
                float vp = __shfl_xor(v, 1, 64);
                if (!(l15 & 1)) {
                    int rowi = (rt << 4) + (quad << 2) + r;
                    h1s[w4][rowi * 68 + (ct << 3) + (l15 >> 1)] = packh2(v, vp);
                }
            }
        }
    }
    // --- L2 MFMA: h2[64 x 128] = h1s[64 x 128] @ WbH; bias+relu; pack to h2s ---
    unsigned* h2w = &u.xs[w4][0];   // h2s region aliases own xs (dead)
#pragma unroll
    for (int ct = 0; ct < 8; ++ct) ba8[ct] = Bb[(ct << 4) + l15];
#pragma unroll 1
    for (int ct = 0; ct < 8; ++ct) {
        f16x8 bfrag[4];
#pragma unroll
        for (int ks = 0; ks < 4; ++ks) {
            uint4 bv = *(const uint4*)&WbH[(size_t)((((ks << 3) | ct) << 6) | lane) << 2];
            __builtin_memcpy(&bfrag[ks], &bv, 16);
        }
#pragma unroll
        for (int rt = 0; rt < 4; ++rt) {
            f32x4 acc = {0.f, 0.f, 0.f, 0.f};
#pragma unroll
            for (int ks = 0; ks < 4; ++ks) {
                f16x8 af;
                uint4 av = *(const uint4*)&h1s[w4][((rt << 4) + l15) * 68 +
                                                   (((ks << 2) + quad) << 2)];
                __builtin_memcpy(&af, &av, 16);
                acc = __builtin_amdgcn_mfma_f32_16x16x32_f16(af, bfrag[ks], acc, 0, 0, 0);
            }
#pragma unroll
            for (int r = 0; r < 4; ++r) {
                float v = fmaxf(acc[r] + ba8[ct], 0.f);
                float vp = __shfl_xor(v, 1, 64);
                if (!(l15 & 1)) {
                    int rowi = (rt << 4) + (quad << 2) + r;
                    int d = (ct << 3) + (l15 >> 1);
                    int ch = d >> 2, din = d & 3;
                    h2w[(rowi << 6) + ((ch ^ (rowi & 15)) << 2) + din] = packh2(v, vp);
                }
            }
        }
    }
    __syncthreads();   // all h2s + nbs visible block-wide
    // --- L3 MFMA: wave w4 owns col-tiles [4*w4, 4*w4+4) of 16 ---
    int ctb = w4 << 2;
    f16x8 cfrag[4][4];   // [ct][ks]
#pragma unroll
    for (int ct = 0; ct < 4; ++ct)
#pragma unroll
        for (int ks = 0; ks < 4; ++ks) {
            uint4 bv = *(const uint4*)&WcH[(size_t)((((ks << 4) | (ctb + ct)) << 6) | lane) << 2];
            __builtin_memcpy(&cfrag[ct][ks], &bv, 16);
        }
#pragma unroll 1
    for (int cent = 0; cent < 4; ++cent) {
        const unsigned* h2r = &u.xs[cent][0];
        int nbc = nbs[cent];
        float runM[4][4];
#pragma unroll
        for (int ct = 0; ct < 4; ++ct)
#pragma unroll
            for (int r = 0; r < 4; ++r) runM[ct][r] = -1e30f;
#pragma unroll
        for (int rt = 0; rt < 4; ++rt) {
            int nl = (rt << 4) + l15;          // A row (neighbor) for this lane
            f16x8 afrag[4];
#pragma unroll
            for (int ks = 0; ks < 4; ++ks) {
                int cp = ((ks << 2) | quad) ^ l15;
                uint4 av = *(const uint4*)&h2r[(nl << 6) + (cp << 2)];
                __builtin_memcpy(&afrag[ks], &av, 16);
            }
#pragma unroll
            for (int ct = 0; ct < 4; ++ct) {
                f32x4 acc = {0.f, 0.f, 0.f, 0.f};
#pragma unroll
                for (int ks = 0; ks < 4; ++ks)
                    acc = __builtin_amdgcn_mfma_f32_16x16x32_f16(afrag[ks], cfrag[ct][ks],
                                                                 acc, 0, 0, 0);
                int nb0 = (rt << 4) + (quad << 2);   // C row = quad*4 + r
#pragma unroll
                for (int r = 0; r < 4; ++r) {
                    float v = (nb0 + r < nbc) ? acc[r] : -1e30f;
                    runM[ct][r] = fmaxf(runM[ct][r], v);
                }
            }
        }
#pragma unroll
        for (int ct = 0; ct < 4; ++ct) {
            float m = fmaxf(fmaxf(runM[ct][0], runM[ct][1]),
                            fmaxf(runM[ct][2], runM[ct][3]));
            m = fmaxf(m, __shfl_xor(m, 16, 64));
            m = fmaxf(m, __shfl_xor(m, 32, 64));
            if (lane < 16) {
                int cc = ((ctb + ct) << 4) | l15;   // C col = lane&15
                Aout[(size_t)((cloud << 8) + centb + cent) * 260 + cc] = m + Bc[cc];
            }
        }
    }
}

// ---------------------------------------------------------------------------
// Barrier-free MFMA GEMM with pre-packed fp16 B: C[M,N] = A[M,K] @ B[K,N].
// One wave owns a 16-row x 128-col C strip. If gmax != null: fused per-cloud
// col max via encoded atomicMax (cloud = row/256).
// ---------------------------------------------------------------------------
__global__ __launch_bounds__(256) void gemm_mfma2(
    const float* __restrict__ A, int lda, const unsigned* __restrict__ Bp, int nct,
    const float* __restrict__ bias, float* __restrict__ C, int ldc, int K,
    int relu, unsigned* __restrict__ gmax) {
    int w = (blockIdx.x << 2) + (TID >> 6);
    int ncg = nct >> 3;
    int rs = w / ncg, cg = w - rs * ncg;
    int r0 = rs << 4, ct0 = cg << 3;
    int lane = TID & 63, quad = lane >> 4, l15 = lane & 15;
    f32x4 acc[8];
#pragma unroll
    for (int ct = 0; ct < 8; ++ct) acc[ct] = (f32x4){0.f, 0.f, 0.f, 0.f};
    const float* ar = A + (size_t)(r0 + l15) * lda;
    int nks = (K + 31) >> 5;
    for (int ks = 0; ks < nks; ++ks) {
        int kb = (ks << 5) + (quad << 3);
        f16x8 af;
        if (kb + 8 <= K) {
            float4 a0 = *(const float4*)(ar + kb);
            float4 a1 = *(const float4*)(ar + kb + 4);
            uint4 av = make_uint4(packh2(a0.x, a0.y), packh2(a0.z, a0.w),
                                  packh2(a1.x, a1.y), packh2(a1.z, a1.w));
            __builtin_memcpy(&af, &av, 16);
        } else {
            float f[8];
#pragma unroll
            for (int j = 0; j < 8; ++j) f[j] = (kb + j < K) ? ar[kb + j] : 0.f;
            uint4 av = make_uint4(packh2(f[0], f[1]), packh2(f[2], f[3]),
                                  packh2(f[4], f[5]), packh2(f[6], f[7]));
            __builtin_memcpy(&af, &av, 16);
        }
#pragma unroll
        for (int ct = 0; ct < 8; ++ct) {
            uint4 bv = *(const uint4*)&Bp[(size_t)(((ks * nct + ct0 + ct) << 6) | lane) << 2];
            f16x8 bf;
            __builtin_memcpy(&bf, &bv, 16);
            acc[ct] = __builtin_amdgcn_mfma_f32_16x16x32_f16(af, bf, acc[ct], 0, 0, 0);
        }
    }
    if (!gmax) {
#pragma unroll
        for (int ct = 0; ct < 8; ++ct) {
            int col = ((ct0 + ct) << 4) + l15;
            float bb = bias[col];
#pragma unroll
            for (int r = 0; r < 4; ++r) {
                int row = r0 + (quad << 2) + r;   // C row = quad*4 + r
                float v = acc[ct][r] + bb;
                if (relu) v = fmaxf(v, 0.f);
                C[(size_t)row * ldc + col] = v;
            }
        }
    } else {
        int cloud = r0 >> 8;
#pragma unroll
        for (int ct = 0; ct < 8; ++ct) {
            int col = ((ct0 + ct) << 4) + l15;
            float bb = bias[col];
            float m = fmaxf(fmaxf(acc[ct][0], acc[ct][1]),
                            fmaxf(acc[ct][2], acc[ct][3])) + bb;
            m = fmaxf(m, __shfl_xor(m, 16, 64));
            m = fmaxf(m, __shfl_xor(m, 32, 64));
            if (quad == 0) atomicMax(&gmax[(cloud << 10) + col], encf(m));
        }
    }
}

// ---------------------------------------------------------------------------
// Head MLP, batched over clouds (weights read ONCE total). Outputs
// bit-identical to the single-block head (same serial ascending-i chains).
// ---------------------------------------------------------------------------
__global__ __launch_bounds__(128) void head1_kernel(
    const unsigned* __restrict__ gfeatE,
    const float* __restrict__ Wh1, const float* __restrict__ bh1,
    float* __restrict__ s1g) {
    int cloud = TID >> 4;
    int col = (blockIdx.x << 4) + (TID & 15);
    float v = bh1[col];
    const unsigned* ge = gfeatE + (cloud << 10);
    for (int i = 0; i < 1024; ++i)
        v = fmaf(decf(ge[i]), Wh1[i * 512 + col], v);
    s1g[(cloud << 9) + col] = fmaxf(v, 0.f);
}

__global__ __launch_bounds__(128) void head2_kernel(
    const float* __restrict__ s1g,
    const float* __restrict__ Wh2, const float* __restrict__ bh2,
    float* __restrict__ s2g) {
    int cloud = TID >> 4;
    int col = (blockIdx.x << 4) + (TID & 15);
    float v = bh2[col];
    const float* s1 = s1g + (cloud << 9);
    for (int i = 0; i < 512; ++i)
        v = fmaf(s1[i], Wh2[i * 256 + col], v);
    s2g[(cloud << 8) + col] = fmaxf(v, 0.f);
}

__global__ __launch_bounds__(64) void head3_kernel(
    const float* __restrict__ s2g,
    const float* __restrict__ Wh3, const float* __restrict__ bh3,
    float* __restrict__ out) {
    __shared__ float lg[10];
    int cloud = blockIdx.x;
    const float* s2 = s2g + (cloud << 8);
    if (TID < 10) {
        float v = bh3[TID];
        for (int i = 0; i < 256; ++i) v = fmaf(s2[i], Wh3[i * 10 + TID], v);
        lg[TID] = v;
    }
    __syncthreads();
    if (TID == 0) {
        float mx = lg[0];
        for (int i = 1; i < 10; ++i) mx = fmaxf(mx, lg[i]);
        float s = 0.f;
        for (int i = 0; i < 10; ++i) s += expf(lg[i] - mx);
        float lse = mx + logf(s);
        for (int i = 0; i < 10; ++i) out[cloud * 10 + i] = lg[i] - lse;
    }
}

// ---------------------------------------------------------------------------
// Launch. Workspace layout (peak 10.4 MB).
// Packed fp16 weights: WcH@335872(64K) WaH@401408(40K) WbH@442368(32K)
//   W1bH@475136(8K) W1cH@483328(16K)
//   W3aH@8945664(144K) W3bH@9093120(256K) W3cH@9355264(1M).
// s1g/s2g live in the h1g region (dead after gemm2).
// ---------------------------------------------------------------------------
extern "C" void kernel_launch(void* const* d_in, const int* in_sizes, int n_in,
                              void* d_out, int out_size, void* d_ws, size_t ws_size,
                              hipStream_t stream) {
    (void)in_sizes; (void)n_in; (void)out_size; (void)ws_size;
    const float* pos = (const float*)d_in[0];
    const float* W1a = (const float*)d_in[1];  const float* b1a = (const float*)d_in[2];
    const float* W1b = (const float*)d_in[3];  const float* b1b = (const float*)d_in[4];
    const float* W1c = (const float*)d_in[5];  const float* b1c = (const float*)d_in[6];
    const float* W2a = (const float*)d_in[7];  const float* b2a = (const float*)d_in[8];
    const float* W2b = (const float*)d_in[9];  const float* b2b = (const float*)d_in[10];
    const float* W2c = (const float*)d_in[11]; const float* b2c = (const float*)d_in[12];
    const float* W3a = (const float*)d_in[13]; const float* b3a = (const float*)d_in[14];
    const float* W3b = (const float*)d_in[15]; const float* b3b = (const float*)d_in[16];
    const float* W3c = (const float*)d_in[17]; const float* b3c = (const float*)d_in[18];
    const float* Wh1 = (const float*)d_in[19]; const float* bh1 = (const float*)d_in[20];
    const float* Wh2 = (const float*)d_in[21]; const float* bh2 = (const float*)d_in[22];
    const float* Wh3 = (const float*)d_in[23]; const float* bh3 = (const float*)d_in[24];

    char* ws = (char*)d_ws;
    float*    curv   = (float*)(ws + 0);
    float4*   pos1   = (float4*)(ws + 98304);
    float*    curv1  = (float*)(ws + 229376);
    float4*   pos2   = (float4*)(ws + 270336);
    unsigned* gfeatE = (unsigned*)(ws + 303104);
    unsigned* WcH    = (unsigned*)(ws + 335872);
    unsigned* WaH    = (unsigned*)(ws + 401408);
    unsigned* WbH    = (unsigned*)(ws + 442368);
    unsigned* W1bH   = (unsigned*)(ws + 475136);
    unsigned* W1cH   = (unsigned*)(ws + 483328);
    float*    x1     = (float*)(ws + 524288);
    float*    Abuf   = (float*)(ws + 4718592);
    float*    h1g    = (float*)(ws + 6848512);
    unsigned* W3aH   = (unsigned*)(ws + 8945664);
    unsigned* W3bH   = (unsigned*)(ws + 9093120);
    unsigned* W3cH   = (unsigned*)(ws + 9355264);
    float*    h2g    = x1;    // x1 dead after conv2
    float*    s1g    = h1g;   // h1g dead after gemm2
    float*    s2g    = h1g + 4096;

    curv_kernel<<<256, 256, 0, stream>>>(pos, curv);
    fps1_pack_kernel<<<404, 256, 0, stream>>>(pos, curv, pos1, curv1,
                                              W2c, W2a, W2b, W3a, W3b, W3c,
                                              W1b, W1c,
                                              WcH, WaH, WbH, W3aH, W3bH, W3cH,
                                              W1bH, W1cH,
                                              gfeatE);
    fps2_conv1_kernel<<<2056, 256, 0, stream>>>(pos, pos1, curv1, pos2, Abuf,
                                                W1a, b1a, W1bH, b1b, W1cH, b1c, x1);
    conv2_kernel<<<512, 256, 0, stream>>>(pos1, pos2, x1, WaH, b2a, WbH, b2b, WcH, b2c,
                                          Abuf);
    gemm_mfma2<<<64, 256, 0, stream>>>(Abuf, 260, W3aH, 16, b3a, h1g, 256,
                                       259, 1, nullptr);
    gemm_mfma2<<<128, 256, 0, stream>>>(h1g, 256, W3bH, 32, b3b, h2g, 512,
                                        256, 1, nullptr);
    gemm_mfma2<<<256, 256, 0, stream>>>(h2g, 512, W3cH, 64, b3c, nullptr, 0,
                                        512, 0, gfeatE);
    head1_kernel<<<32, 128, 0, stream>>>(gfeatE, Wh1, bh1, s1g);
    head2_kernel<<<16, 128, 0, stream>>>(s1g, Wh2, bh2, s2g);
    head3_kernel<<<8, 64, 0, stream>>>(s2g, Wh3, bh3, (float*)d_out);
}

// Round 12
// 1047.645 us; speedup vs baseline: 1.0248x; 1.0248x over previous
//
#include <hip/hip_runtime.h>
#include <hip/hip_fp16.h>
#include <math.h>

#define TID threadIdx.x

typedef _Float16 h2vec __attribute__((ext_vector_type(2)));
typedef _Float16 f16x8 __attribute__((ext_vector_type(8)));
typedef float f32x4 __attribute__((ext_vector_type(4)));
typedef float f32x2v __attribute__((ext_vector_type(2)));

#if __has_builtin(__builtin_elementwise_fma)
#define EFMA(a, b, c) __builtin_elementwise_fma((a), (b), (c))
#else
static __device__ __forceinline__ f32x2v EFMA(f32x2v a, f32x2v b, f32x2v c) {
    f32x2v r;
    r.x = fmaf(a.x, b.x, c.x);
    r.y = fmaf(a.y, b.y, c.y);
    return r;
}
#endif

// fp16 pair dot into fp32 accumulator: v_dot2_f32_f16
static __device__ __forceinline__ float fdot2(unsigned a, unsigned b, float c) {
    h2vec av, bv;
    __builtin_memcpy(&av, &a, 4);
    __builtin_memcpy(&bv, &b, 4);
    return __builtin_amdgcn_fdot2(av, bv, c, false);
}

static __device__ __forceinline__ unsigned packh2(float a, float b) {
    __half2 hh = __floats2half2_rn(a, b);
    unsigned u;
    __builtin_memcpy(&u, &hh, 4);
    return u;
}

// Monotone float<->uint encoding for integer atomicMax on floats.
static __device__ __forceinline__ unsigned encf(float f) {
    unsigned u = __float_as_uint(f);
    return (u >> 31) ? ~u : (u | 0x80000000u);
}
static __device__ __forceinline__ float decf(unsigned e) {
    unsigned u = (e >> 31) ? (e & 0x7fffffffu) : ~e;
    return __uint_as_float(u);
}

// Wave-uniform sum via DPP ladder; only lane63 true total, readlane broadcasts.
static __device__ __forceinline__ int wave_sum(int v) {
    v += __builtin_amdgcn_update_dpp(0, v, 0x111, 0xf, 0xf, true);  // row_shr:1
    v += __builtin_amdgcn_update_dpp(0, v, 0x112, 0xf, 0xf, true);  // row_shr:2
    v += __builtin_amdgcn_update_dpp(0, v, 0x114, 0xf, 0xf, true);  // row_shr:4
    v += __builtin_amdgcn_update_dpp(0, v, 0x118, 0xf, 0xf, true);  // row_shr:8
    v += __builtin_amdgcn_update_dpp(0, v, 0x142, 0xf, 0xf, true);  // row_bcast15
    v += __builtin_amdgcn_update_dpp(0, v, 0x143, 0xf, 0xf, true);  // row_bcast31
    return __builtin_amdgcn_readlane(v, 63);
}

// u64 max with partner brought in by DPP; bound_ctrl=true shifts in 0 (identity).
template <int CTRL>
static __device__ __forceinline__ unsigned long long dpp_max_u64(unsigned long long k) {
    int lo = (int)(unsigned)(k & 0xffffffffULL);
    int hi = (int)(unsigned)(k >> 32);
    int lo2 = __builtin_amdgcn_update_dpp(0, lo, CTRL, 0xf, 0xf, true);
    int hi2 = __builtin_amdgcn_update_dpp(0, hi, CTRL, 0xf, 0xf, true);
    unsigned long long k2 = ((unsigned long long)(unsigned)hi2 << 32) | (unsigned)lo2;
    return k2 > k ? k2 : k;
}

// ---------------------------------------------------------------------------
// fp32 -> fp16 B-fragment pack for mfma_f32_16x16x32_f16 (one slot per t).
// ---------------------------------------------------------------------------
static __device__ __forceinline__ void pack_slot(const float* __restrict__ W,
                                                 unsigned* __restrict__ out,
                                                 int K, int ncols, int t) {
    int lane = t & 63;
    int frag = t >> 6;
    int nct = ncols >> 4;
    int ks = frag / nct, ct = frag - ks * nct;
    int kbase = (ks << 5) + ((lane >> 4) << 3);
    int cc = (ct << 4) + (lane & 15);
    unsigned o[4];
#pragma unroll
    for (int i = 0; i < 4; ++i) {
        int k0 = kbase + 2 * i, k1 = kbase + 2 * i + 1;
        float f0 = (k0 < K) ? W[(size_t)k0 * ncols + cc] : 0.f;
        float f1 = (k1 < K) ? W[(size_t)k1 * ncols + cc] : 0.f;
        o[i] = packh2(f0, f1);
    }
    *(uint4*)&out[(size_t)t * 4] = make_uint4(o[0], o[1], o[2], o[3]);
}

// ---------------------------------------------------------------------------
// Curvature: per-point 10-NN covariance, lambda_min / sum(lambda).
// Round-5 proven: 4 sub-lanes per point, disjoint 512-ranges, exact
// lexicographic (d2, idx) 4-way merge — bit-identical, measured -122 us.
// ---------------------------------------------------------------------------
__global__ __launch_bounds__(256) void curv_kernel(const float* __restrict__ pos,
                                                   float* __restrict__ curv) {
    __shared__ float4 sp[2048];
    __shared__ float smd[64][40];   // [pt][sub*10+t]
    __shared__ int smi[64][40];
    int cloud = blockIdx.x >> 5;
    int base = cloud << 11;
    for (int j = TID; j < 2048; j += 256) {
        const float* p = pos + (size_t)(base + j) * 3;
        float x = p[0], y = p[1], z = p[2];
        sp[j] = make_float4(x, y, z, fmaf(x, x, fmaf(y, y, z * z)));
    }
    __syncthreads();
    int pt = TID >> 2;                       // 0..63: point within block
    int sub = TID & 3;                       // 0..3: candidate range
    int li = ((blockIdx.x & 31) << 6) + pt;  // point within cloud
    float4 pi = sp[li];
    float bd[10];
    int bi[10];
#pragma unroll
    for (int t = 0; t < 10; ++t) { bd[t] = 3.0e38f; bi[t] = 0; }
    int j0 = sub << 9;
    for (int jj = 0; jj < 512; ++jj) {
        int j = j0 + jj;
        float4 pj = sp[j];
        float dot = fmaf(pi.x, pj.x, fmaf(pi.y, pj.y, pi.z * pj.z));
        float d2 = pi.w + pj.w - 2.0f * dot;   // same form as reference _sqdist
        if (d2 < bd[9]) {
            bd[9] = d2; bi[9] = j;
#pragma unroll
            for (int t = 9; t > 0; --t) {
                if (bd[t] < bd[t - 1]) {
                    float td = bd[t]; bd[t] = bd[t - 1]; bd[t - 1] = td;
                    int ti = bi[t]; bi[t] = bi[t - 1]; bi[t - 1] = ti;
                }
            }
        }
    }
#pragma unroll
    for (int t = 0; t < 10; ++t) {
        smd[pt][sub * 10 + t] = bd[t];
        smi[pt][sub * 10 + t] = bi[t];
    }
    __syncthreads();
    // exact 4-way lex-(d2,idx) merge; all 4 subs compute redundantly
    float d0 = smd[pt][0], d1 = smd[pt][10], d2h = smd[pt][20], d3 = smd[pt][30];
    int i0 = smi[pt][0], i1 = smi[pt][10], i2 = smi[pt][20], i3 = smi[pt][30];
    int h0 = 0, h1 = 0, h2c = 0, h3 = 0;
    int mbi[10];
#pragma unroll
    for (int t = 0; t < 10; ++t) {
        bool a01 = (d1 < d0) || (d1 == d0 && i1 < i0);
        float dA = a01 ? d1 : d0; int iA = a01 ? i1 : i0;
        bool a23 = (d3 < d2h) || (d3 == d2h && i3 < i2);
        float dB = a23 ? d3 : d2h; int iB = a23 ? i3 : i2;
        bool ab = (dB < dA) || (dB == dA && iB < iA);
        mbi[t] = ab ? iB : iA;
        if (ab) {
            if (a23) { ++h3; d3 = (h3 < 10) ? smd[pt][30 + h3] : 3.0e38f;
                       i3 = (h3 < 10) ? smi[pt][30 + h3] : 0x7fffffff; }
            else     { ++h2c; d2h = (h2c < 10) ? smd[pt][20 + h2c] : 3.0e38f;
                       i2 = (h2c < 10) ? smi[pt][20 + h2c] : 0x7fffffff; }
        } else {
            if (a01) { ++h1; d1 = (h1 < 10) ? smd[pt][10 + h1] : 3.0e38f;
                       i1 = (h1 < 10) ? smi[pt][10 + h1] : 0x7fffffff; }
            else     { ++h0; d0 = (h0 < 10) ? smd[pt][h0] : 3.0e38f;
                       i0 = (h0 < 10) ? smi[pt][h0] : 0x7fffffff; }
        }
    }
    if (sub != 0) return;
    double sx = 0, sy = 0, sz = 0;
#pragma unroll
    for (int t = 0; t < 10; ++t) { float4 p = sp[mbi[t]]; sx += p.x; sy += p.y; sz += p.z; }
    double mx = sx / 10.0, my = sy / 10.0, mz = sz / 10.0;
    double cxx = 0, cxy = 0, cxz = 0, cyy = 0, cyz = 0, czz = 0;
#pragma unroll
    for (int t = 0; t < 10; ++t) {
        float4 p = sp[mbi[t]];
        double dx = p.x - mx, dy = p.y - my, dz = p.z - mz;
        cxx += dx * dx; cxy += dx * dy; cxz += dx * dz;
        cyy += dy * dy; cyz += dy * dz; czz += dz * dz;
    }
    cxx /= 10.0; cxy /= 10.0; cxz /= 10.0; cyy /= 10.0; cyz /= 10.0; czz /= 10.0;
    double q = (cxx + cyy + czz) / 3.0;
    double b00 = cxx - q, b11 = cyy - q, b22 = czz - q;
    double p2 = b00 * b00 + b11 * b11 + b22 * b22 +
                2.0 * (cxy * cxy + cxz * cxz + cyz * cyz);
    double lmin;
    if (p2 <= 0.0) {
        lmin = q;
    } else {
        double p = sqrt(p2 / 6.0);
        double inv = 1.0 / p;
        double c00 = b00 * inv, c01 = cxy * inv, c02 = cxz * inv;
        double c11 = b11 * inv, c12 = cyz * inv, c22 = b22 * inv;
        double detB = c00 * (c11 * c22 - c12 * c12)
                    - c01 * (c01 * c22 - c12 * c02)
                    + c02 * (c01 * c12 - c11 * c02);
        double r = 0.5 * detB;
        r = fmin(1.0, fmax(-1.0, r));
        double phi = acos(r) / 3.0;
        lmin = q + 2.0 * p * cos(phi + 2.0943951023931953);  // smallest eigenvalue
    }
    double s3 = cxx + cyy + czz;
    curv[base + li] = (float)(lmin / (s3 + 1e-8));
}

// ---------------------------------------------------------------------------
// Weighted FPS body — round-0 proven structure (measured best). Do not touch.
// ---------------------------------------------------------------------------
template <int N, int M, int SLOTS>
static __device__ void fps_body(
    const float* __restrict__ srcpos, int stride, const float* __restrict__ srccurv,
    int cloud, float4* __restrict__ outPos, float* __restrict__ outCurv,
    float* __restrict__ outA, int ldA,
    float4* sp, int* sidx, unsigned long long* rec /* [8] */) {
    constexpr int PAIRS = SLOTS / 2;
    const float* cp = srcpos + (size_t)cloud * N * stride;
    for (int j = TID; j < N; j += 256)
        sp[j] = make_float4(cp[j * stride], cp[j * stride + 1], cp[j * stride + 2], 0.f);
    if (TID == 0) sidx[0] = 0;
    __syncthreads();
    f32x2v px[PAIRS], py[PAIRS], pz[PAIRS], md[PAIRS], wvv[PAIRS];
#pragma unroll
    for (int s = 0; s < PAIRS; ++s) {
        int p0 = ((2 * s) << 8) + TID, p1 = ((2 * s + 1) << 8) + TID;
        float4 q0 = sp[p0], q1 = sp[p1];
        px[s].x = q0.x; px[s].y = q1.x;
        py[s].x = q0.y; py[s].y = q1.y;
        pz[s].x = q0.z; pz[s].y = q1.z;
        md[s].x = 3.0e38f; md[s].y = 3.0e38f;
        wvv[s].x = fmaf(10.0f, srccurv[cloud * N + p0], 1.0f);
        wvv[s].y = fmaf(10.0f, srccurv[cloud * N + p1], 1.0f);
    }
    int lane = TID & 63, w4 = TID >> 6;
    float4 c0 = sp[0];
    float cx = c0.x, cy = c0.y, cz = c0.z;
    for (int t = 1; t < M; ++t) {
        f32x2v cxv, cyv, czv;
        cxv.x = cx; cxv.y = cx; cyv.x = cy; cyv.y = cy; czv.x = cz; czv.y = cz;
        unsigned long long kk[PAIRS];
#pragma unroll
        for (int s = 0; s < PAIRS; ++s) {
            f32x2v dx = px[s] - cxv, dy = py[s] - cyv, dz = pz[s] - czv;
            f32x2v nd = EFMA(dx, dx, EFMA(dy, dy, dz * dz));
            f32x2v m2 = __builtin_elementwise_min(md[s], nd);
            md[s] = m2;
            f32x2v sc = m2 * wvv[s];
            // score >= 0 -> float bits monotone under unsigned compare
            unsigned long long k0 =
                ((unsigned long long)__float_as_uint(sc.x) << 32) |
                (unsigned)(2047 - (((2 * s) << 8) + TID));
            unsigned long long k1 =
                ((unsigned long long)__float_as_uint(sc.y) << 32) |
                (unsigned)(2047 - (((2 * s + 1) << 8) + TID));
            kk[s] = k0 > k1 ? k0 : k1;
        }
        unsigned long long k = kk[0];
#pragma unroll
        for (int s = 1; s < PAIRS; ++s) k = kk[s] > k ? kk[s] : k;
        k = dpp_max_u64<0x111>(k);   // row_shr:1
        k = dpp_max_u64<0x112>(k);   // row_shr:2
        k = dpp_max_u64<0x114>(k);   // row_shr:4
        k = dpp_max_u64<0x118>(k);   // row_shr:8
        k = dpp_max_u64<0x142>(k);   // row_bcast15
        k = dpp_max_u64<0x143>(k);   // row_bcast31 -> lane63 has wave max
        int pbase = (t & 1) << 2;
        if (lane == 63) rec[pbase | w4] = k;
        __syncthreads();
        unsigned long long k0 = rec[pbase + 0];
        unsigned long long k1 = rec[pbase + 1];
        unsigned long long k2 = rec[pbase + 2];
        unsigned long long k3 = rec[pbase + 3];
        unsigned long long ka = k0 > k1 ? k0 : k1;
        unsigned long long kb = k2 > k3 ? k2 : k3;
        unsigned long long km = ka > kb ? ka : kb;
        int nbix = 2047 - (int)(unsigned)(km & 0xffffffffULL);  // uniform winner
        if (TID == 0) sidx[t] = nbix;
        float4 cc = sp[nbix];        // uniform (broadcast) read
        cx = cc.x; cy = cc.y; cz = cc.z;
    }
    __syncthreads();
    for (int j = TID; j < M; j += 256) {
        int id = sidx[j];
        float4 qv = sp[id];
        outPos[cloud * M + j] = qv;
        if (outCurv) outCurv[cloud * M + j] = srccurv[cloud * N + id];
        if (outA) {
            float* a = outA + (size_t)(cloud * M + j) * ldA;
            a[256] = qv.x; a[257] = qv.y; a[258] = qv.z;
        }
    }
}

// ---------------------------------------------------------------------------
// fps1 + weight packing in one launch. Blocks 0-7: fps1 (serial, 8 CUs for
// ~425 us). Blocks 8-403: fragment-pack the 8 weight matrices (independent
// of fps1; hidden entirely under its shadow). Block 8 inits gfeat encodings.
// ---------------------------------------------------------------------------
__global__ __launch_bounds__(256, 1) void fps1_pack_kernel(
    const float* __restrict__ pos, const float* __restrict__ curv,
    float4* __restrict__ pos1, float* __restrict__ curv1,
    const float* __restrict__ Wc, const float* __restrict__ Wa,
    const float* __restrict__ Wb, const float* __restrict__ W3a,
    const float* __restrict__ W3b, const float* __restrict__ W3c,
    const float* __restrict__ W1b, const float* __restrict__ W1c,
    unsigned* __restrict__ WcH, unsigned* __restrict__ WaH,
    unsigned* __restrict__ WbH, unsigned* __restrict__ W3aH,
    unsigned* __restrict__ W3bH, unsigned* __restrict__ W3cH,
    unsigned* __restrict__ W1bH, unsigned* __restrict__ W1cH,
    unsigned* __restrict__ gfeatE) {
    __shared__ float4 sp[2048];
    __shared__ int sidx[1024];
    __shared__ unsigned long long rec[8];
    if (blockIdx.x < 8) {
        fps_body<2048, 1024, 8>(pos, 3, curv, blockIdx.x, pos1, curv1, nullptr, 0,
                                sp, sidx, rec);
        return;
    }
    int b = blockIdx.x - 8;
    if (b == 0)
        for (int i = TID; i < 8192; i += 256) gfeatE[i] = 0u;  // enc identity
    if (b < 16)        pack_slot(Wc,  WcH,  128, 256,  b * 256 + TID);
    else if (b < 26)   pack_slot(Wa,  WaH,  131, 128,  (b - 16) * 256 + TID);
    else if (b < 34)   pack_slot(Wb,  WbH,  128, 128,  (b - 26) * 256 + TID);
    else if (b < 70)   pack_slot(W3a, W3aH, 259, 256,  (b - 34) * 256 + TID);
    else if (b < 134)  pack_slot(W3b, W3bH, 256, 512,  (b - 70) * 256 + TID);
    else if (b < 390)  pack_slot(W3c, W3cH, 512, 1024, (b - 134) * 256 + TID);
    else if (b < 392)  pack_slot(W1b, W1bH, 64, 64,    (b - 390) * 256 + TID);
    else               pack_slot(W1c, W1cH, 64, 128,   (b - 392) * 256 + TID);
}

// ---------------------------------------------------------------------------
// Exact top-64 (smallest d2, idx tie-break), register-resident, atomic-free.
// Keep-set identical to the original LDS select_k64; sel ORDER differs, which
// is fine — aggregation is max (order-free) and masks are count-based.
// ---------------------------------------------------------------------------
template <int NCH>
static __device__ __forceinline__ int select_k64_reg(
    const unsigned* __restrict__ ck, const int* __restrict__ ci,
    int c, int lane, int* sel, int* nbOut) {
    if (c <= 64) {
        *nbOut = c;
        return (lane < c) ? ci[lane] : 0;
    }
    unsigned long long kq[NCH];
    bool act[NCH];
#pragma unroll
    for (int q = 0; q < NCH; ++q) {
        int idx = (q << 6) + lane;
        bool v = idx < c;
        act[q] = v;
        kq[q] = v ? (((unsigned long long)ck[idx] << 32) | (unsigned)ci[idx]) : 0ULL;
    }
    int excess = c - 64;
    if (excess <= 24) {
        for (int r = 0; r < excess; ++r) {
            unsigned long long k = 0;
#pragma unroll
            for (int q = 0; q < NCH; ++q) {
                unsigned long long kc = act[q] ? kq[q] : 0ULL;
                k = kc > k ? kc : k;
            }
            k = dpp_max_u64<0x111>(k);
            k = dpp_max_u64<0x112>(k);
            k = dpp_max_u64<0x114>(k);
            k = dpp_max_u64<0x118>(k);
            k = dpp_max_u64<0x142>(k);
            k = dpp_max_u64<0x143>(k);
            unsigned klo = (unsigned)__builtin_amdgcn_readlane(
                (int)(unsigned)(k & 0xffffffffULL), 63);
            unsigned khi = (unsigned)__builtin_amdgcn_readlane(
                (int)(unsigned)(k >> 32), 63);
            unsigned long long km = ((unsigned long long)khi << 32) | klo;
#pragma unroll
            for (int q = 0; q < NCH; ++q)
                if (act[q] && kq[q] == km) act[q] = false;
        }
    } else {
        unsigned T = 0;
        for (int bit = 31; bit >= 0; --bit) {
            unsigned mid = T | (1u << bit);
            int cl = 0;
#pragma unroll
            for (int q = 0; q < NCH; ++q)
                cl += (act[q] && (unsigned)(kq[q] >> 32) < mid) ? 1 : 0;
            if (wave_sum(cl) < 64) T = mid;
        }
        int cl = 0;
#pragma unroll
        for (int q = 0; q < NCH; ++q)
            cl += (act[q] && (unsigned)(kq[q] >> 32) < T) ? 1 : 0;
        int need = 64 - wave_sum(cl);
        int TI = 0;
        for (int bit = 11; bit >= 0; --bit) {
            int mid = TI | (1 << bit);
            int ce = 0;
#pragma unroll
            for (int q = 0; q < NCH; ++q)
                ce += (act[q] && (unsigned)(kq[q] >> 32) == T &&
                       (int)(unsigned)(kq[q] & 0xffffffffULL) < mid) ? 1 : 0;
            if (wave_sum(ce) < need) TI = mid;
        }
#pragma unroll
        for (int q = 0; q < NCH; ++q) {
            unsigned hi = (unsigned)(kq[q] >> 32);
            int lo = (int)(unsigned)(kq[q] & 0xffffffffULL);
            act[q] = act[q] && (hi < T || (hi == T && lo <= TI));
        }
    }
    int base = 0;
#pragma unroll
    for (int q = 0; q < NCH; ++q) {
        unsigned long long m = __ballot(act[q]);
        if (act[q]) {
            int off = __popcll(m & ((1ULL << lane) - 1));
            sel[base + off] = (int)(unsigned)(kq[q] & 0xffffffffULL);
        }
        base += __popcll(m);
    }
    *nbOut = 64;
    return sel[lane];
}

// ---------------------------------------------------------------------------
// SA1 conv body (3->64->64->128). Round-9 proven: L2/L3 as MFMA GEMMs, h1
// fp32 scalar, fp16 LDS rows (36-dword stride), in-place L2 write-back,
// masked row-max L3. Value path verified absmax 0.0.
// ---------------------------------------------------------------------------
union U1 {
    struct {
        float4 sp[2048];
        unsigned ck[4][256];
        int ci[4][256];
        int sel[4][64];
    } p;                      // 41 KB
    unsigned hs[4][2304];     // 36 KB: 64 rows x 36 dwords (h1 then h2, fp16 pairs)
};

static __device__ void conv1_body(
    int bid, U1& u,
    const float* __restrict__ pos, const float4* __restrict__ pos1,
    const float* __restrict__ W1, const float* __restrict__ B1,
    const unsigned* __restrict__ W1bH, const float* __restrict__ B2,
    const unsigned* __restrict__ W1cH, const float* __restrict__ B3,
    float* __restrict__ x1) {
    __shared__ int nbs[4];
    int cloud = bid >> 8;
    int w4 = TID >> 6, lane = TID & 63;
    int quad = lane >> 4, l15 = lane & 15;
    int centb = (bid & 255) << 2;
    int g = (cloud << 10) + centb + w4;
    int base = cloud << 11;
    for (int j = TID; j < 2048; j += 256) {
        const float* p = pos + (size_t)(base + j) * 3;
        u.p.sp[j] = make_float4(p[0], p[1], p[2], 0.f);
    }
    __syncthreads();
    float4 cq = pos1[g];
    double cx = cq.x, cy = cq.y, cz = cq.z;
    int cnt = 0;   // wave-uniform running candidate count
    for (int s = 0; s < 32; ++s) {
        int j = (s << 6) + lane;
        float4 pj = u.p.sp[j];
        double dx = (double)pj.x - cx, dy = (double)pj.y - cy, dz = (double)pj.z - cz;
        double d2 = dx * dx + dy * dy + dz * dz;
        bool in = (d2 <= 0.2 * 0.2);
        unsigned long long m = __ballot(in);
        if (in) {
            int p = cnt + __popcll(m & ((1ULL << lane) - 1));
            if (p < 256) {
                u.p.ck[w4][p] = __float_as_uint((float)d2);
                u.p.ci[w4][p] = j;
            }
        }
        cnt += __popcll(m);
    }
    int c = min(cnt, 256);
    int nb;
    int idxn = select_k64_reg<4>(u.p.ck[w4], u.p.ci[w4], c, lane, u.p.sel[w4], &nb);
    if (lane == 0) nbs[w4] = nb;
    float4 pn = u.p.sp[idxn];
    float rx = pn.x - cq.x, ry = pn.y - cq.y, rz = pn.z - cq.z;
    // h1 fp32 (exact): 64 ch, 3 FMAs each
    float h1[64];
#pragma unroll
    for (int cc2 = 0; cc2 < 64; ++cc2) {
        float v = fmaf(rx, W1[cc2], fmaf(ry, W1[64 + cc2], fmaf(rz, W1[128 + cc2], B1[cc2])));
        h1[cc2] = fmaxf(v, 0.f);
    }
    __syncthreads();   // all waves done with p region -> hs free
    // stage h1 -> hs fp16 pairs, row = lane, 36-dword stride
    {
        unsigned* row = &u.hs[w4][lane * 36];
#pragma unroll
        for (int q = 0; q < 8; ++q) {
            *(uint4*)&row[q << 2] =
                make_uint4(packh2(h1[8 * q + 0], h1[8 * q + 1]),
                           packh2(h1[8 * q + 2], h1[8 * q + 3]),
                           packh2(h1[8 * q + 4], h1[8 * q + 5]),
                           packh2(h1[8 * q + 6], h1[8 * q + 7]));
        }
    }
    __syncthreads();   // h1 rows visible (same wave + lockstep safety)
    // --- L2 MFMA: h2[64x64] = h1 @ W1b (K=64: 2 ks; 64 cols: 4 ct) ---
    {
        f16x8 bfrag[2][4];
#pragma unroll
        for (int ks = 0; ks < 2; ++ks)
#pragma unroll
            for (int ct = 0; ct < 4; ++ct) {
                uint4 bv = *(const uint4*)&W1bH[(size_t)(
                    (((ks << 2) | ct) << 6) | lane) << 2];
                __builtin_memcpy(&bfrag[ks][ct], &bv, 16);
            }
        f16x8 af[4][2];
#pragma unroll
        for (int rt = 0; rt < 4; ++rt)
#pragma unroll
            for (int ks = 0; ks < 2; ++ks) {
                uint4 av = *(const uint4*)&u.hs[w4][((rt << 4) + l15) * 36 +
                                                    (((ks << 2) | quad) << 2)];
                __builtin_memcpy(&af[rt][ks], &av, 16);
            }
        float ba4[4];
#pragma unroll
        for (int ct = 0; ct < 4; ++ct) ba4[ct] = B2[(ct << 4) + l15];
#pragma unroll
        for (int rt = 0; rt < 4; ++rt) {
#pragma unroll
            for (int ct = 0; ct < 4; ++ct) {
                f32x4 acc = {0.f, 0.f, 0.f, 0.f};
#pragma unroll
                for (int ks = 0; ks < 2; ++ks)
                    acc = __builtin_amdgcn_mfma_f32_16x16x32_f16(
                        af[rt][ks], bfrag[ks][ct], acc, 0, 0, 0);
#pragma unroll
                for (int r = 0; r < 4; ++r) {
                    float v = fmaxf(acc[r] + ba4[ct], 0.f);
                    float vp = __shfl_xor(v, 1, 64);
                    if (!(l15 & 1)) {
                        int rowi = (rt << 4) + (quad << 2) + r;
                        u.hs[w4][rowi * 36 + (ct << 3) + (l15 >> 1)] = packh2(v, vp);
                    }
                }
            }
        }
    }
    __syncthreads();   // h2 rows + nbs visible block-wide
    // --- L3 MFMA: msg[64x128] = h2 @ W1c (K=64: 2 ks; 128 cols: 8 ct) ---
    {
        int ct2 = w4 << 1;
        f16x8 cfrag[2][2];   // [ctl][ks]
#pragma unroll
        for (int ctl = 0; ctl < 2; ++ctl)
#pragma unroll
            for (int ks = 0; ks < 2; ++ks) {
                uint4 bv = *(const uint4*)&W1cH[(size_t)(
                    (((ks << 3) | (ct2 + ctl)) << 6) | lane) << 2];
                __builtin_memcpy(&cfrag[ctl][ks], &bv, 16);
            }
#pragma unroll 1
        for (int cent = 0; cent < 4; ++cent) {
            int nbc = nbs[cent];
            float runM[2][4];
#pragma unroll
            for (int ctl = 0; ctl < 2; ++ctl)
#pragma unroll
                for (int r = 0; r < 4; ++r) runM[ctl][r] = -1e30f;
#pragma unroll
            for (int rt = 0; rt < 4; ++rt) {
                f16x8 af[2];
#pragma unroll
                for (int ks = 0; ks < 2; ++ks) {
                    uint4 av = *(const uint4*)&u.hs[cent][((rt << 4) + l15) * 36 +
                                                          (((ks << 2) | quad) << 2)];
                    __builtin_memcpy(&af[ks], &av, 16);
                }
#pragma unroll
                for (int ctl = 0; ctl < 2; ++ctl) {
                    f32x4 acc = {0.f, 0.f, 0.f, 0.f};
#pragma unroll
                    for (int ks = 0; ks < 2; ++ks)
                        acc = __builtin_amdgcn_mfma_f32_16x16x32_f16(
                            af[ks], cfrag[ctl][ks], acc, 0, 0, 0);
                    int nb0 = (rt << 4) + (quad << 2);
#pragma unroll
                    for (int r = 0; r < 4; ++r) {
                        float v = (nb0 + r < nbc) ? acc[r] : -1e30f;
                        runM[ctl][r] = fmaxf(runM[ctl][r], v);
                    }
                }
            }
#pragma unroll
            for (int ctl = 0; ctl < 2; ++ctl) {
                float m = fmaxf(fmaxf(runM[ctl][0], runM[ctl][1]),
                                fmaxf(runM[ctl][2], runM[ctl][3]));
                m = fmaxf(m, __shfl_xor(m, 16, 64));
                m = fmaxf(m, __shfl_xor(m, 32, 64));
                if (lane < 16) {
                    int cc = ((ct2 + ctl) << 4) | l15;
                    x1[(size_t)((cloud << 10) + centb + cent) * 128 + cc] = m + B3[cc];
                }
            }
        }
    }
}

// ---------------------------------------------------------------------------
// Merged launch: blocks 0-7 run fps2 (1024->256), blocks 8.. run conv1.
// (setprio on fps2 measured neutral in round 10 — removed.) 3 blocks/CU.
// ---------------------------------------------------------------------------
union UM {
    U1 c;
    struct {
        float4 sp[1024];
        unsigned long long rec[8];
        int sidx[256];
    } f;
};

__global__ __launch_bounds__(256, 3) void fps2_conv1_kernel(
    const float* __restrict__ pos, const float4* __restrict__ pos1,
    const float* __restrict__ curv1, float4* __restrict__ pos2,
    float* __restrict__ Abuf,
    const float* __restrict__ W1, const float* __restrict__ B1,
    const unsigned* __restrict__ W1bH, const float* __restrict__ B2,
    const unsigned* __restrict__ W1cH, const float* __restrict__ B3,
    float* __restrict__ x1) {
    __shared__ UM u;
    if (blockIdx.x < 8) {
        fps_body<1024, 256, 4>((const float*)pos1, 4, curv1, blockIdx.x, pos2,
                               nullptr, Abuf, 260, u.f.sp, u.f.sidx, u.f.rec);
    } else {
        conv1_body(blockIdx.x - 8, u.c, pos, pos1, W1, B1, W1bH, B2, W1cH, B3, x1);
    }
}

// ---------------------------------------------------------------------------
// SA2: radius r=0.4 grouping + PointNetConv(131->128->128->256).
// Round-11/12: 512 threads (8 waves vs 4 on the CU). Grouping+select stay on
// one wave per centroid (even waves; odd waves wait — keeps the proven select
// intact); selected rows published via selS (OUTSIDE the union so xs staging
// can't clobber it). xs staging / L1 / L2 split across the wave pair (disjoint
// q-chunks / ct-columns — XOR swizzle is a per-row bijection so no write
// collisions); L3 splits 16 col-tiles across 8 waves. Per-output arithmetic
// instruction-identical to the 4-wave version.
// ---------------------------------------------------------------------------
union U2 {
    struct {
        float4 sp[1024];
        unsigned ck[4][512];
        int ci[4][512];
    } p;
    unsigned xs[4][5376];   // 84 dwords/row x 64 rows; h2s[cent]=xs[cent][0..4095]
};

__global__ __launch_bounds__(512, 1) void conv2_kernel(
    const float4* __restrict__ pos1, const float4* __restrict__ pos2,
    const float* __restrict__ x1,
    const unsigned* __restrict__ WaH, const float* __restrict__ Ba,
    const unsigned* __restrict__ WbH, const float* __restrict__ Bb,
    const unsigned* __restrict__ WcH, const float* __restrict__ Bc,
    float* __restrict__ Aout) {
    __shared__ U2 u;
    __shared__ unsigned h1s[4][4352];   // 68 dwords/row x 64 rows (fp16 pairs)
    __shared__ int selS[4][64];
    __shared__ int nbs[4];
    int cloud = blockIdx.x >> 6;
    int w8 = TID >> 6, lane = TID & 63;
    int centb = (blockIdx.x & 63) << 2;
    int cent = w8 >> 1;                 // 0..3
    bool wA = (w8 & 1) == 0;
    int g = (cloud << 8) + centb + cent;
    int quad = lane >> 4, l15 = lane & 15;
    for (int j = TID; j < 1024; j += 512) u.p.sp[j] = pos1[(cloud << 10) + j];
    __syncthreads();
    float4 cq = pos2[g];
    int idxn = 0;
    float rx = 0.f, ry = 0.f, rz = 0.f;
    if (wA) {
        double cx = cq.x, cy = cq.y, cz = cq.z;
        int cnt = 0;   // wave-uniform running candidate count
        for (int s = 0; s < 16; ++s) {
            int j = (s << 6) + lane;
            float4 pj = u.p.sp[j];
            double dx = (double)pj.x - cx, dy = (double)pj.y - cy, dz = (double)pj.z - cz;
            double d2 = dx * dx + dy * dy + dz * dz;
            bool in = (d2 <= 0.4 * 0.4);
            unsigned long long m = __ballot(in);
            if (in) {
                int p = cnt + __popcll(m & ((1ULL << lane) - 1));
                if (p < 512) {
                    u.p.ck[cent][p] = __float_as_uint((float)d2);
                    u.p.ci[cent][p] = j;
                }
            }
            cnt += __popcll(m);
        }
        int c = min(cnt, 512);
        int nb;
        idxn = select_k64_reg<8>(u.p.ck[cent], u.p.ci[cent], c, lane, selS[cent], &nb);
        if (lane == 0) nbs[cent] = nb;
        selS[cent][lane] = idxn;       // publish in BOTH select paths
        float4 pn = u.p.sp[idxn];
        rx = pn.x - cq.x; ry = pn.y - cq.y; rz = pn.z - cq.z;
    }
    __syncthreads();   // sel/nbs visible; grouping LDS dead -> xs may overwrite
    if (!wA) idxn = selS[cent][lane];
    // --- stage xs: lane = row; wave pair splits q-chunks (A: 0-7, B: 8-15) ---
    {
        const float4* xr = (const float4*)(x1 + (size_t)((cloud << 10) + idxn) * 128);
        unsigned* row = &u.xs[cent][lane * 84];
        int q0 = wA ? 0 : 8;
#pragma unroll
        for (int qi = 0; qi < 8; ++qi) {
            int q = q0 + qi;
            float4 a = xr[q * 2], b = xr[q * 2 + 1];
            *(uint4*)&row[q << 2] = make_uint4(packh2(a.x, a.y), packh2(a.z, a.w),
                                               packh2(b.x, b.y), packh2(b.z, b.w));
        }
        if (wA) {
            *(uint4*)&row[64] = make_uint4(packh2(rx, ry), packh2(rz, 0.f), 0u, 0u);
            *(uint4*)&row[68] = make_uint4(0u, 0u, 0u, 0u);
            *(uint4*)&row[72] = make_uint4(0u, 0u, 0u, 0u);
            *(uint4*)&row[76] = make_uint4(0u, 0u, 0u, 0u);
        }
    }
    __syncthreads();   // xs rows complete (both halves)
    // --- L1 MFMA: wave pair splits ct (A: 0-3, B: 4-7) ---
    int ctb4 = (w8 & 1) << 2;
    float ba4[4];
#pragma unroll
    for (int c4 = 0; c4 < 4; ++c4) ba4[c4] = Ba[((ctb4 + c4) << 4) + l15];
#pragma unroll 1
    for (int c4 = 0; c4 < 4; ++c4) {
        int ct = ctb4 + c4;
        f16x8 bfrag[5];
#pragma unroll
        for (int ks = 0; ks < 5; ++ks) {
            uint4 bv = *(const uint4*)&WaH[(size_t)((((ks << 3) | ct) << 6) | lane) << 2];
            __builtin_memcpy(&bfrag[ks], &bv, 16);
        }
#pragma unroll
        for (int rt = 0; rt < 4; ++rt) {
            f32x4 acc = {0.f, 0.f, 0.f, 0.f};
#pragma unroll
            for (int ks = 0; ks < 5; ++ks) {
                f16x8 af;
                uint4 av = *(const uint4*)&u.xs[cent][((rt << 4) + l15) * 84 +
                                                      (((ks << 2) + quad) << 2)];
                __builtin_memcpy(&af, &av, 16);
                acc = __builtin_amdgcn_mfma_f32_16x16x32_f16(af, bfrag[ks], acc, 0, 0, 0);
            }
#pragma unroll
            for (int r = 0; r < 4; ++r) {
                float v = fmaxf(acc[r] + ba4[c4], 0.f);
                float vp = __shfl_xor(v, 1, 64);
                if (!(l15 & 1)) {
                    int rowi = (rt << 4) + (quad << 2) + r;
                    h1s[cent][rowi * 68 + (ct << 3) + (l15 >> 1)] = packh2(v, vp);
                }
            }
        }
    }
    __syncthreads();   // h1s rows complete per centroid (pair)
    // --- L2 MFMA: wave pair splits ct (A: 0-3, B: 4-7) ---
    unsigned* h2w = &u.xs[cent][0];   // h2s region aliases own xs (dead)
#pragma unroll
    for (int c4 = 0; c4 < 4; ++c4) ba4[c4] = Bb[((ctb4 + c4) << 4) + l15];
#pragma unroll 1
    for (int c4 = 0; c4 < 4; ++c4) {
        int ct = ctb4 + c4;
        f16x8 bfrag[4];
#pragma unroll
        for (int ks = 0; ks < 4; ++ks) {
            uint4 bv = *(const uint4*)&WbH[(size_t)((((ks << 3) | ct) << 6) | lane) << 2];
            __builtin_memcpy(&bfrag[ks], &bv, 16);
        }
#pragma unroll
        for (int rt = 0; rt < 4; ++rt) {
            f32x4 acc = {0.f, 0.f, 0.f, 0.f};
#pragma unroll
            for (int ks = 0; ks < 4; ++ks) {
                f16x8 af;
                uint4 av = *(const uint4*)&h1s[cent][((rt << 4) + l15) * 68 +
                                                     (((ks << 2) + quad) << 2)];
                __builtin_memcpy(&af, &av, 16);
                acc = __builtin_amdgcn_mfma_f32_16x16x32_f16(af, bfrag[ks], acc, 0, 0, 0);
            }
#pragma unroll
            for (int r = 0; r < 4; ++r) {
                float v = fmaxf(acc[r] + ba4[c4], 0.f);
                float vp = __shfl_xor(v, 1, 64);
                if (!(l15 & 1)) {
                    int rowi = (rt << 4) + (quad << 2) + r;
                    int d = (ct << 3) + (l15 >> 1);
                    int ch = d >> 2, din = d & 3;
                    h2w[(rowi << 6) + ((ch ^ (rowi & 15)) << 2) + din] = packh2(v, vp);
                }
            }
        }
    }
    __syncthreads();   // all h2s + nbs visible block-wide
    // --- L3 MFMA: wave w8 owns col-tiles [2*w8, 2*w8+2) of 16 ---
    int ctb2 = w8 << 1;
    f16x8 cfrag[2][4];   // [ctl][ks]
#pragma unroll
    for (int ctl = 0; ctl < 2; ++ctl)
#pragma unroll
        for (int ks = 0; ks < 4; ++ks) {
            uint4 bv = *(const uint4*)&WcH[(size_t)((((ks << 4) | (ctb2 + ctl)) << 6) | lane) << 2];
            __builtin_memcpy(&cfrag[ctl][ks], &bv, 16);
        }
#pragma unroll 1
    for (int ce = 0; ce < 4; ++ce) {
        const unsigned* h2r = &u.xs[ce][0];
        int nbc = nbs[ce];
        float runM[2][4];
#pragma unroll
        for (int ctl = 0; ctl < 2; ++ctl)
#pragma unroll
            for (int r = 0; r < 4; ++r) runM[ctl][r] = -1e30f;
#pragma unroll
        for (int rt = 0; rt < 4; ++rt) {
            int nl = (rt << 4) + l15;          // A row (neighbor) for this lane
            f16x8 afrag[4];
#pragma unroll
            for (int ks = 0; ks < 4; ++ks) {
                int cp = ((ks << 2) | quad) ^ l15;
                uint4 av = *(const uint4*)&h2r[(nl << 6) + (cp << 2)];
                __builtin_memcpy(&afrag[ks], &av, 16);
            }
#pragma unroll
            for (int ctl = 0; ctl < 2; ++ctl) {
                f32x4 acc = {0.f, 0.f, 0.f, 0.f};
#pragma unroll
                for (int ks = 0; ks < 4; ++ks)
                    acc = __builtin_amdgcn_mfma_f32_16x16x32_f16(afrag[ks], cfrag[ctl][ks],
                                                                 acc, 0, 0, 0);
                int nb0 = (rt << 4) + (quad << 2);   // C row = quad*4 + r
#pragma unroll
                for (int r = 0; r < 4; ++r) {
                    float v = (nb0 + r < nbc) ? acc[r] : -1e30f;
                    runM[ctl][r] = fmaxf(runM[ctl][r], v);
                }
            }
        }
#pragma unroll
        for (int ctl = 0; ctl < 2; ++ctl) {
            float m = fmaxf(fmaxf(runM[ctl][0], runM[ctl][1]),
                            fmaxf(runM[ctl][2], runM[ctl][3]));
            m = fmaxf(m, __shfl_xor(m, 16, 64));
            m = fmaxf(m, __shfl_xor(m, 32, 64));
            if (lane < 16) {
                int cc = ((ctb2 + ctl) << 4) | l15;   // C col = lane&15
                Aout[(size_t)((cloud << 8) + centb + ce) * 260 + cc] = m + Bc[cc];
            }
        }
    }
}

// ---------------------------------------------------------------------------
// Barrier-free MFMA GEMM with pre-packed fp16 B: C[M,N] = A[M,K] @ B[K,N].
// One wave owns a 16-row x 128-col C strip. If gmax != null: fused per-cloud
// col max via encoded atomicMax (cloud = row/256).
// ---------------------------------------------------------------------------
__global__ __launch_bounds__(256) void gemm_mfma2(
    const float* __restrict__ A, int lda, const unsigned* __restrict__ Bp, int nct,
    const float* __restrict__ bias, float* __restrict__ C, int ldc, int K,
    int relu, unsigned* __restrict__ gmax) {
    int w = (blockIdx.x << 2) + (TID >> 6);
    int ncg = nct >> 3;
    int rs = w / ncg, cg = w - rs * ncg;
    int r0 = rs << 4, ct0 = cg << 3;
    int lane = TID & 63, quad = lane >> 4, l15 = lane & 15;
    f32x4 acc[8];
#pragma unroll
    for (int ct = 0; ct < 8; ++ct) acc[ct] = (f32x4){0.f, 0.f, 0.f, 0.f};
    const float* ar = A + (size_t)(r0 + l15) * lda;
    int nks = (K + 31) >> 5;
    for (int ks = 0; ks < nks; ++ks) {
        int kb = (ks << 5) + (quad << 3);
        f16x8 af;
        if (kb + 8 <= K) {
            float4 a0 = *(const float4*)(ar + kb);
            float4 a1 = *(const float4*)(ar + kb + 4);
            uint4 av = make_uint4(packh2(a0.x, a0.y), packh2(a0.z, a0.w),
                                  packh2(a1.x, a1.y), packh2(a1.z, a1.w));
            __builtin_memcpy(&af, &av, 16);
        } else {
            float f[8];
#pragma unroll
            for (int j = 0; j < 8; ++j) f[j] = (kb + j < K) ? ar[kb + j] : 0.f;
            uint4 av = make_uint4(packh2(f[0], f[1]), packh2(f[2], f[3]),
                                  packh2(f[4], f[5]), packh2(f[6], f[7]));
            __builtin_memcpy(&af, &av, 16);
        }
#pragma unroll
        for (int ct = 0; ct < 8; ++ct) {
            uint4 bv = *(const uint4*)&Bp[(size_t)(((ks * nct + ct0 + ct) << 6) | lane) << 2];
            f16x8 bf;
            __builtin_memcpy(&bf, &bv, 16);
            acc[ct] = __builtin_amdgcn_mfma_f32_16x16x32_f16(af, bf, acc[ct], 0, 0, 0);
        }
    }
    if (!gmax) {
#pragma unroll
        for (int ct = 0; ct < 8; ++ct) {
            int col = ((ct0 + ct) << 4) + l15;
            float bb = bias[col];
#pragma unroll
            for (int r = 0; r < 4; ++r) {
                int row = r0 + (quad << 2) + r;   // C row = quad*4 + r
                float v = acc[ct][r] + bb;
                if (relu) v = fmaxf(v, 0.f);
                C[(size_t)row * ldc + col] = v;
            }
        }
    } else {
        int cloud = r0 >> 8;
#pragma unroll
        for (int ct = 0; ct < 8; ++ct) {
            int col = ((ct0 + ct) << 4) + l15;
            float bb = bias[col];
            float m = fmaxf(fmaxf(acc[ct][0], acc[ct][1]),
                            fmaxf(acc[ct][2], acc[ct][3])) + bb;
            m = fmaxf(m, __shfl_xor(m, 16, 64));
            m = fmaxf(m, __shfl_xor(m, 32, 64));
            if (quad == 0) atomicMax(&gmax[(cloud << 10) + col], encf(m));
        }
    }
}

// ---------------------------------------------------------------------------
// Head MLP, batched over clouds (weights read ONCE total). Outputs
// bit-identical to the single-block head (same serial ascending-i chains).
// ---------------------------------------------------------------------------
__global__ __launch_bounds__(128) void head1_kernel(
    const unsigned* __restrict__ gfeatE,
    const float* __restrict__ Wh1, const float* __restrict__ bh1,
    float* __restrict__ s1g) {
    int cloud = TID >> 4;
    int col = (blockIdx.x << 4) + (TID & 15);
    float v = bh1[col];
    const unsigned* ge = gfeatE + (cloud << 10);
    for (int i = 0; i < 1024; ++i)
        v = fmaf(decf(ge[i]), Wh1[i * 512 + col], v);
    s1g[(cloud << 9) + col] = fmaxf(v, 0.f);
}

__global__ __launch_bounds__(128) void head2_kernel(
    const float* __restrict__ s1g,
    const float* __restrict__ Wh2, const float* __restrict__ bh2,
    float* __restrict__ s2g) {
    int cloud = TID >> 4;
    int col = (blockIdx.x << 4) + (TID & 15);
    float v = bh2[col];
    const float* s1 = s1g + (cloud << 9);
    for (int i = 0; i < 512; ++i)
        v = fmaf(s1[i], Wh2[i * 256 + col], v);
    s2g[(cloud << 8) + col] = fmaxf(v, 0.f);
}

__global__ __launch_bounds__(64) void head3_kernel(
    const float* __restrict__ s2g,
    const float* __restrict__ Wh3, const float* __restrict__ bh3,
    float* __restrict__ out) {
    __shared__ float lg[10];
    int cloud = blockIdx.x;
    const float* s2 = s2g + (cloud << 8);
    if (TID < 10) {
        float v = bh3[TID];
        for (int i = 0; i < 256; ++i) v = fmaf(s2[i], Wh3[i * 10 + TID], v);
        lg[TID] = v;
    }
    __syncthreads();
    if (TID == 0) {
        float mx = lg[0];
        for (int i = 1; i < 10; ++i) mx = fmaxf(mx, lg[i]);
        float s = 0.f;
        for (int i = 0; i < 10; ++i) s += expf(lg[i] - mx);
        float lse = mx + logf(s);
        for (int i = 0; i < 10; ++i) out[cloud * 10 + i] = lg[i] - lse;
    }
}

// ---------------------------------------------------------------------------
// Launch. Workspace layout (peak 10.4 MB).
// Packed fp16 weights: WcH@335872(64K) WaH@401408(40K) WbH@442368(32K)
//   W1bH@475136(8K) W1cH@483328(16K)
//   W3aH@8945664(144K) W3bH@9093120(256K) W3cH@9355264(1M).
// s1g/s2g live in the h1g region (dead after gemm2).
// ---------------------------------------------------------------------------
extern "C" void kernel_launch(void* const* d_in, const int* in_sizes, int n_in,
                              void* d_out, int out_size, void* d_ws, size_t ws_size,
                              hipStream_t stream) {
    (void)in_sizes; (void)n_in; (void)out_size; (void)ws_size;
    const float* pos = (const float*)d_in[0];
    const float* W1a = (const float*)d_in[1];  const float* b1a = (const float*)d_in[2];
    const float* W1b = (const float*)d_in[3];  const float* b1b = (const float*)d_in[4];
    const float* W1c = (const float*)d_in[5];  const float* b1c = (const float*)d_in[6];
    const float* W2a = (const float*)d_in[7];  const float* b2a = (const float*)d_in[8];
    const float* W2b = (const float*)d_in[9];  const float* b2b = (const float*)d_in[10];
    const float* W2c = (const float*)d_in[11]; const float* b2c = (const float*)d_in[12];
    const float* W3a = (const float*)d_in[13]; const float* b3a = (const float*)d_in[14];
    const float* W3b = (const float*)d_in[15]; const float* b3b = (const float*)d_in[16];
    const float* W3c = (const float*)d_in[17]; const float* b3c = (const float*)d_in[18];
    const float* Wh1 = (const float*)d_in[19]; const float* bh1 = (const float*)d_in[20];
    const float* Wh2 = (const float*)d_in[21]; const float* bh2 = (const float*)d_in[22];
    const float* Wh3 = (const float*)d_in[23]; const float* bh3 = (const float*)d_in[24];

    char* ws = (char*)d_ws;
    float*    curv   = (float*)(ws + 0);
    float4*   pos1   = (float4*)(ws + 98304);
    float*    curv1  = (float*)(ws + 229376);
    float4*   pos2   = (float4*)(ws + 270336);
    unsigned* gfeatE = (unsigned*)(ws + 303104);
    unsigned* WcH    = (unsigned*)(ws + 335872);
    unsigned* WaH    = (unsigned*)(ws + 401408);
    unsigned* WbH    = (unsigned*)(ws + 442368);
    unsigned* W1bH   = (unsigned*)(ws + 475136);
    unsigned* W1cH   = (unsigned*)(ws + 483328);
    float*    x1     = (float*)(ws + 524288);
    float*    Abuf   = (float*)(ws + 4718592);
    float*    h1g    = (float*)(ws + 6848512);
    unsigned* W3aH   = (unsigned*)(ws + 8945664);
    unsigned* W3bH   = (unsigned*)(ws + 9093120);
    unsigned* W3cH   = (unsigned*)(ws + 9355264);
    float*    h2g    = x1;    // x1 dead after conv2
    float*    s1g    = h1g;   // h1g dead after gemm2
    float*    s2g    = h1g + 4096;

    curv_kernel<<<256, 256, 0, stream>>>(pos, curv);
    fps1_pack_kernel<<<404, 256, 0, stream>>>(pos, curv, pos1, curv1,
                                              W2c, W2a, W2b, W3a, W3b, W3c,
                                              W1b, W1c,
                                              WcH, WaH, WbH, W3aH, W3bH, W3cH,
                                              W1bH, W1cH,
                                              gfeatE);
    fps2_conv1_kernel<<<2056, 256, 0, stream>>>(pos, pos1, curv1, pos2, Abuf,
                                                W1a, b1a, W1bH, b1b, W1cH, b1c, x1);
    conv2_kernel<<<512, 512, 0, stream>>>(pos1, pos2, x1, WaH, b2a, WbH, b2b, WcH, b2c,
                                          Abuf);
    gemm_mfma2<<<64, 256, 0, stream>>>(Abuf, 260, W3aH, 16, b3a, h1g, 256,
                                       259, 1, nullptr);
    gemm_mfma2<<<128, 256, 0, stream>>>(h1g, 256, W3bH, 32, b3b, h2g, 512,
                                        256, 1, nullptr);
    gemm_mfma2<<<256, 256, 0, stream>>>(h2g, 512, W3cH, 64, b3c, nullptr, 0,
                                        512, 0, gfeatE);
    head1_kernel<<<32, 128, 0, stream>>>(gfeatE, Wh1, bh1, s1g);
    head2_kernel<<<16, 128, 0, stream>>>(s1g, Wh2, bh2, s2g);
    head3_kernel<<<8, 64, 0, stream>>>(s2g, Wh3, bh3, (float*)d_out);
}